// Round 7
// baseline (337.442 us; speedup 1.0000x reference)
//
#include <hip/hip_runtime.h>
#include <math.h>

typedef _Float16 f16;
typedef _Float16 f16x8 __attribute__((ext_vector_type(8)));
typedef __fp16 h2 __attribute__((ext_vector_type(2)));
typedef float f32x4 __attribute__((ext_vector_type(4)));
typedef unsigned int uint32;
typedef unsigned short ushort16;

#define NSAMP 131072
#define DD 12
#define LLAYERS 4
#define KK 8
#define BV 3.0f
#define BLK 256
#define NLW 17920   // f16 elems per (net,layer): 512 (W0+b0) + 8192 (Wh) + 9216 (Wl)
#define WS_WH 512
#define WS_WL 8704
#define THROW 152   // th row: 152 f16 = 304 B (19 dw -> stride 12 mod 32, 2-way, aligned 16)
#define XROW 24     // xst row: 24 f16 = 48 B (12 dw stride, 2-way, aligned 16)

__device__ __forceinline__ uint32 packh(float a, float b){
    union { f16 h; ushort16 u; } x, y;
    x.h = (f16)a; y.h = (f16)b;
    return (uint32)x.u | ((uint32)y.u << 16);
}
__device__ __forceinline__ float unpl(uint32 v){ union { ushort16 u; f16 h; } c; c.u = (ushort16)v; return (float)c.h; }
__device__ __forceinline__ float unph(uint32 v){ union { ushort16 u; f16 h; } c; c.u = (ushort16)(v >> 16); return (float)c.h; }

__device__ __forceinline__ h2 u2h(uint32 x){ union { uint32 u; h2 h; } c; c.u = x; return c.h; }
__device__ __forceinline__ uint32 h2u(h2 x){ union { h2 h; uint32 u; } c; c.h = x; return c.u; }
// leaky(x) = max(x, 0.2x) for slope<1 — no cmp/cndmask
__device__ __forceinline__ h2 lk2(h2 x){
    h2 k = { (__fp16)0.2f, (__fp16)0.2f };
    return __builtin_elementwise_max(x, x * k);
}
__device__ __forceinline__ h2 pkrtz(float a, float b){ return __builtin_amdgcn_cvt_pkrtz(a, b); }

__device__ __forceinline__ f32x4 MF(f16x8 a, f16x8 b, f32x4 c){
    return __builtin_amdgcn_mfma_f32_16x16x32_f16(a, b, c, 0, 0, 0);
}

// act tile: per-wave [64 samples][64 feats] f16, row=128B, XOR-swizzled by ((s&7)<<4)
__device__ __forceinline__ const f16x8* actRd(const f16* actW, int s, int fb){
    return (const f16x8*)((const char*)actW + s * 128 + (fb ^ ((s & 7) << 4)));
}
__device__ __forceinline__ uint2* actWr(f16* actW, int s, int fb){
    return (uint2*)((char*)actW + s * 128 + (fb ^ ((s & 7) << 4)));
}

// ---------------- prep: weights -> fp16 hi/lo fragments (final layer M-permuted to
// spline order m = dd*24+p); biases packed half2; conv W and logdet const ----------------
extern "C" __global__ void nsflow_prep(
        const float* __restrict__ n1W0, const float* __restrict__ n1Wh, const float* __restrict__ n1Wl,
        const float* __restrict__ n1b0, const float* __restrict__ n1bh, const float* __restrict__ n1bl,
        const float* __restrict__ n2W0, const float* __restrict__ n2Wh, const float* __restrict__ n2Wl,
        const float* __restrict__ n2b0, const float* __restrict__ n2bh, const float* __restrict__ n2bl,
        const float* __restrict__ c1W0, const float* __restrict__ c1Wh, const float* __restrict__ c1Wl,
        const float* __restrict__ c1b0, const float* __restrict__ c1bh, const float* __restrict__ c1bl,
        const float* __restrict__ c2W0, const float* __restrict__ c2Wh, const float* __restrict__ c2Wl,
        const float* __restrict__ c2b0, const float* __restrict__ c2bh, const float* __restrict__ c2bl,
        const float* __restrict__ convP, const float* __restrict__ convS,
        const float* __restrict__ convL, const float* __restrict__ convU,
        f16* __restrict__ ws_hi, f16* __restrict__ ws_lo,
        uint32* __restrict__ wsbc, uint32* __restrict__ wsbh, float* __restrict__ wsWc){
    int NL = blockIdx.y;                      // l*4 + net; net: 0=c1 1=n1 2=c2 3=n2
    int off = blockIdx.x * 256 + threadIdx.x;
    int layer = NL >> 2, net = NL & 3;

    const float *W0, *Wh, *Wl, *b0, *bh; int nin;
    if (net == 0){ W0 = c1W0; Wh = c1Wh; Wl = c1Wl; b0 = c1b0; bh = c1bh; nin = 4; }
    else if (net == 1){ W0 = n1W0; Wh = n1Wh; Wl = n1Wl; b0 = n1b0; bh = n1bh; nin = 6; }
    else if (net == 2){ W0 = c2W0; Wh = c2Wh; Wl = c2Wl; b0 = c2b0; bh = c2bh; nin = 4; }
    else { W0 = n2W0; Wh = n2Wh; Wl = n2Wl; b0 = n2b0; bh = n2bh; nin = 6; }

    if (off < 17920){
        float w = 0.f;
        if (off < 512){                          // W0^T frags: [mt(4)][16 lanes][8 j]; j==7 -> bias
            int mt = off >> 7, r = off & 127, ln = r >> 3, j = r & 7;
            int row = mt * 16 + ln;
            if (j < nin) w = W0[(layer * nin + j) * 64 + row];
            else if (j == 7) w = b0[layer * 64 + row];
        } else if (off < 8704){                  // Wh^T frags: [h(2)][mt*2+ks (8)][64 lanes][8 j]
            int o = off - 512; int h = o >> 12; o &= 4095;
            int t = o >> 9, ln = (o >> 3) & 63, j = o & 7;
            int mt = t >> 1, ks = t & 1;
            int k = ks * 32 + (ln >> 4) * 8 + j, row = mt * 16 + (ln & 15);
            w = Wh[((layer * 2 + h) * 64 + k) * 64 + row];
        } else {                                 // Wl^T frags, M-permuted: m = dd*24+p -> f = dd*23+p
            int o = off - 8704;
            int t = o >> 9, ln = (o >> 3) & 63, j = o & 7;
            int mt = t >> 1, ks = t & 1;
            int k = ks * 32 + (ln >> 4) * 8 + j, m = mt * 16 + (ln & 15);
            int dd = m / 24, p = m - dd * 24;
            if (p < 23) w = Wl[(layer * 64 + k) * 138 + dd * 23 + p];
        }
        f16 hi = (f16)w;
        f16 lo = (f16)(w - (float)hi);
        ws_hi[NL * NLW + off] = hi;
        ws_lo[NL * NLW + off] = lo;
    } else if (off < 18064){                     // final-layer bias half2 pairs (cond [0..71], net [72..143])
        int mm = off - 17920;
        if (net == 0 || net == 2){
            int halfI = net >> 1;
            int s = layer * 2 + halfI;
            bool isn = mm >= 72;
            int m0 = 2 * (isn ? mm - 72 : mm);
            const float* bb = isn ? (halfI ? n2bl : n1bl) : (halfI ? c2bl : c1bl);
            int dd0 = m0 / 24, p0 = m0 - dd0 * 24;
            int m1 = m0 + 1;
            int dd1 = m1 / 24, p1 = m1 - dd1 * 24;
            float v0 = (p0 < 23) ? bb[layer * 138 + dd0 * 23 + p0] : 0.f;
            float v1 = (p1 < 23) ? bb[layer * 138 + dd1 * 23 + p1] : 0.f;
            wsbc[s * 144 + mm] = packh(v0, v1);
        }
    } else if (off < 18128){                     // hidden bias half2 pairs: [NL][h(2)][32]
        int q = off - 18064;
        int h = q >> 5, r = q & 31, m0 = 2 * r;
        wsbh[NL * 64 + q] = packh(bh[(layer * 2 + h) * 64 + m0], bh[(layer * 2 + h) * 64 + m0 + 1]);
    } else if (off < 18705 && NL == 0){          // conv W = P(L+I)(U+diag(S)) and logdet const
        int idx = off - 18128;
        if (idx < 576){
            int l = idx / 144, r = idx - l * 144;
            int i = r / 12, j = r - i * 12;
            const float* P = convP + l * 144;
            const float* Lm = convL + l * 144;
            const float* Um = convU + l * 144;
            const float* Sv = convS + l * 12;
            float acc = 0.f;
            for (int a = 0; a < 12; ++a){
                float inner = 0.f;
                for (int bb2 = 0; bb2 < 12; ++bb2){
                    float m1 = (bb2 < a) ? Lm[a * 12 + bb2] : (bb2 == a ? 1.f : 0.f);
                    float m2 = (j > bb2) ? Um[bb2 * 12 + j] : (j == bb2 ? Sv[j] : 0.f);
                    inner = fmaf(m1, m2, inner);
                }
                acc = fmaf(P[i * 12 + a], inner, acc);
            }
            wsWc[idx] = acc;
        } else if (idx == 576){
            float sacc = 0.f;
            for (int q2 = 0; q2 < LLAYERS * 12; ++q2) sacc += __logf(fabsf(convS[q2]));
            wsWc[576] = sacc;
        }
    }
}

// ---------------- GEMM helpers ----------------
// first layer, conditioner: B built by shuffle from per-thread xc regs; bias folded (B slot7=1)
__device__ __forceinline__ void gemmL0c(const f16* __restrict__ ah, const f16* __restrict__ al,
                                        int xc0, int xc1, f16* actW, int lane){
    int l15 = lane & 15, g = lane >> 4;
    f16x8 Z = {};
    f16x8 Bf[4];
#pragma unroll
    for (int nt = 0; nt < 4; ++nt){
        union { uint4 u; f16x8 v; } cc;
        cc.u.x = (uint32)__shfl(xc0, nt * 16 + l15, 64);
        cc.u.y = (uint32)__shfl(xc1, nt * 16 + l15, 64);
        cc.u.z = 0u;
        cc.u.w = 0x3C000000u;   // slots 6,7 = (0, 1.0h)
        Bf[nt] = cc.v;
    }
    bool g0 = (g == 0);
#pragma unroll
    for (int mt = 0; mt < 4; ++mt){
        f16x8 Ah = g0 ? *(const f16x8*)(ah + (mt * 16 + l15) * 8) : Z;
        f16x8 Al = g0 ? *(const f16x8*)(al + (mt * 16 + l15) * 8) : Z;
#pragma unroll
        for (int nt = 0; nt < 4; ++nt){
            f32x4 acc = {0.f, 0.f, 0.f, 0.f};
            acc = MF(Ah, Bf[nt], acc);
            acc = MF(Al, Bf[nt], acc);
            uint2 v = { h2u(lk2(pkrtz(acc[0], acc[1]))), h2u(lk2(pkrtz(acc[2], acc[3]))) };
            *actWr(actW, nt * 16 + l15, mt * 32 + g * 8) = v;
        }
    }
}

// first layer, data net: B from xstS rows (bias folded, slot 7/15 = 1.0)
__device__ __forceinline__ void gemmL0n(const f16* __restrict__ ah, const f16* __restrict__ al,
                                        const f16* src, int offE,
                                        f16* actW, int lane, int widS){
    int l15 = lane & 15, g = lane >> 4;
    f16x8 Z = {};
    f16x8 Bf[4];
#pragma unroll
    for (int nt = 0; nt < 4; ++nt)
        Bf[nt] = *(const f16x8*)(src + (widS + nt * 16 + l15) * XROW + offE);
    bool g0 = (g == 0);
#pragma unroll
    for (int mt = 0; mt < 4; ++mt){
        f16x8 Ah = g0 ? *(const f16x8*)(ah + (mt * 16 + l15) * 8) : Z;
        f16x8 Al = g0 ? *(const f16x8*)(al + (mt * 16 + l15) * 8) : Z;
#pragma unroll
        for (int nt = 0; nt < 4; ++nt){
            f32x4 acc = {0.f, 0.f, 0.f, 0.f};
            acc = MF(Ah, Bf[nt], acc);
            acc = MF(Al, Bf[nt], acc);
            uint2 v = { h2u(lk2(pkrtz(acc[0], acc[1]))), h2u(lk2(pkrtz(acc[2], acc[3]))) };
            *actWr(actW, nt * 16 + l15, mt * 32 + g * 8) = v;
        }
    }
}

// hidden 64->64, in place; bias as packed half2 pairs (32 u32 per layer-half)
__device__ __forceinline__ void gemm64(const f16* __restrict__ ah, const f16* __restrict__ al,
                                       const uint32* __restrict__ bq,
                                       f16* actW, int lane){
    int l15 = lane & 15, g = lane >> 4;
    f16x8 Bf[4][2];
#pragma unroll
    for (int nt = 0; nt < 4; ++nt)
#pragma unroll
        for (int ks = 0; ks < 2; ++ks)
            Bf[nt][ks] = *actRd(actW, nt * 16 + l15, ks * 64 + g * 16);
#pragma unroll
    for (int mt = 0; mt < 4; ++mt){
        f16x8 Ah0 = *(const f16x8*)(ah + ((mt * 2 + 0) * 64 + lane) * 8);
        f16x8 Ah1 = *(const f16x8*)(ah + ((mt * 2 + 1) * 64 + lane) * 8);
        f16x8 Al0 = *(const f16x8*)(al + ((mt * 2 + 0) * 64 + lane) * 8);
        f16x8 Al1 = *(const f16x8*)(al + ((mt * 2 + 1) * 64 + lane) * 8);
        uint2 bp = *(const uint2*)(bq + mt * 8 + g * 2);
#pragma unroll
        for (int nt = 0; nt < 4; ++nt){
            f32x4 acc = {0.f, 0.f, 0.f, 0.f};
            acc = MF(Ah0, Bf[nt][0], acc);
            acc = MF(Al0, Bf[nt][0], acc);
            acc = MF(Ah1, Bf[nt][1], acc);
            acc = MF(Al1, Bf[nt][1], acc);
            uint2 v = { h2u(lk2(pkrtz(acc[0], acc[1]) + u2h(bp.x))),
                        h2u(lk2(pkrtz(acc[2], acc[3]) + u2h(bp.y))) };
            *actWr(actW, nt * 16 + l15, mt * 32 + g * 8) = v;
        }
    }
}

// spline for one chunk of 16 samples; lane L ends with 6-dim logdet sum for sample sbase+(L&15)
__device__ __forceinline__ float spline_chunk(const f16* thW, f16* xst,
                                              int sbase, int halfI, int lane){
    float vsum = 0.f;
#pragma unroll 1
    for (int pass = 0; pass < 2; ++pass){
        if (pass == 1 && lane >= 32) break;
        int dd = pass * 4 + (lane >> 4);
        int s16 = lane & 15;

        const f16* tr = thW + s16 * THROW + dd * 24;
        f16x8 t0 = *(const f16x8*)(tr);
        f16x8 t1 = *(const f16x8*)(tr + 8);
        f16x8 t2 = *(const f16x8*)(tr + 16);
        float th[23];
#pragma unroll
        for (int j = 0; j < 8; ++j) th[j] = (float)t0[j];
#pragma unroll
        for (int j = 0; j < 8; ++j) th[8 + j] = (float)t1[j];
#pragma unroll
        for (int j = 0; j < 7; ++j) th[16 + j] = (float)t2[j];

        float mw = th[0];
#pragma unroll
        for (int j = 1; j < KK; ++j) mw = fmaxf(mw, th[j]);
        float ew[KK]; float swsum = 0.f;
#pragma unroll
        for (int j = 0; j < KK; ++j){ ew[j] = __expf(th[j] - mw); swsum += ew[j]; }
        float iw_ = 6.0f / swsum;
        float mh = th[KK];
#pragma unroll
        for (int j = 1; j < KK; ++j) mh = fmaxf(mh, th[KK + j]);
        float eh[KK]; float shsum = 0.f;
#pragma unroll
        for (int j = 0; j < KK; ++j){ eh[j] = __expf(th[KK + j] - mh); shsum += eh[j]; }
        float ih_ = 6.0f / shsum;
        float dv[KK + 1];
        dv[0] = 1.0f; dv[KK] = 1.0f;
#pragma unroll
        for (int j = 0; j < KK - 1; ++j){
            float v = th[2 * KK + j];
            float z = __expf(-fabsf(v));
            dv[j + 1] = fmaxf(v, 0.f) + __logf(1.0f + z);
        }

        int sidx = sbase + s16;
        int slot = halfI ? dd : 8 + dd;
        float X = (float)xst[sidx * XROW + slot];
        float Xc = fminf(fmaxf(X, -BV), BV);

        float cx = -BV, cy = -BV;
        float xk = -BV, xk1 = BV, yk = -BV, yk1 = BV, dk = 1.0f, dk1 = 1.0f;
#pragma unroll
        for (int j = 0; j < KK; ++j){
            float nx = (j == KK - 1) ? (BV + 1e-6f) : (cx + ew[j] * iw_);
            float ny = (j == KK - 1) ? BV : (cy + eh[j] * ih_);
            bool sel = (j == 0) || (Xc >= cx);
            if (sel){ xk = cx; xk1 = nx; yk = cy; yk1 = ny; dk = dv[j]; dk1 = dv[j + 1]; }
            cx = nx; cy = ny;
        }
        float idx_ = 1.0f / (xk1 - xk);
        float s_ = (yk1 - yk) * idx_;
        float xi = (Xc - xk) * idx_;
        float om = 1.0f - xi;
        float xo = xi * om;
        float den = s_ + (dk1 + dk - 2.0f * s_) * xo;
        float Y = yk + (yk1 - yk) * (s_ * xi * xi + dk * xo) / den;
        float dydx = s_ * s_ * (dk1 * xi * xi + 2.0f * s_ * xo + dk * om * om) / (den * den);
        bool inside = (X <= BV) && (X >= -BV);
        float Yo = inside ? Y : X;
        float ldv = inside ? __logf(dydx) : 0.f;
        xst[sidx * XROW + slot] = (f16)Yo;
        vsum += ldv;
    }
    vsum += __shfl_xor(vsum, 16, 64);
    vsum += __shfl_xor(vsum, 32, 64);
    return vsum;
}

// one tail chunk NT: fused cond+net finals per mt (packed epilogue, single b64 th write),
// then spline. No persistent per-lane output array (rule #20).
#define TAILP(NT, BCA, BCB)                                                            \
{                                                                                      \
    f16x8 Bna = *actRd(actW, NT * 16 + l15, g * 16);                                   \
    f16x8 Bnb = *actRd(actW, NT * 16 + l15, 64 + g * 16);                              \
    _Pragma("unroll")                                                                  \
    for (int mt = 0; mt < 9; ++mt){                                                    \
        const f16* pch = whC + WS_WL + (mt * 128 + lane) * 8;                          \
        const f16* pcl = wlC + WS_WL + (mt * 128 + lane) * 8;                          \
        const f16* pnh = whN + WS_WL + (mt * 128 + lane) * 8;                          \
        const f16* pnl = wlN + WS_WL + (mt * 128 + lane) * 8;                          \
        f16x8 AhC0 = *(const f16x8*)(pch);                                             \
        f16x8 AhC1 = *(const f16x8*)(pch + 512);                                       \
        f16x8 AlC0 = *(const f16x8*)(pcl);                                             \
        f16x8 AlC1 = *(const f16x8*)(pcl + 512);                                       \
        f16x8 AhN0 = *(const f16x8*)(pnh);                                             \
        f16x8 AhN1 = *(const f16x8*)(pnh + 512);                                       \
        f16x8 AlN0 = *(const f16x8*)(pnl);                                             \
        f16x8 AlN1 = *(const f16x8*)(pnl + 512);                                       \
        uint2 cq = *(const uint2*)(bcn + mt * 8 + g * 2);                              \
        uint2 nq = *(const uint2*)(bcn + 72 + mt * 8 + g * 2);                         \
        f32x4 ac = {0.f,0.f,0.f,0.f}, an = {0.f,0.f,0.f,0.f};                          \
        ac = MF(AhC0, BCA, ac); ac = MF(AlC0, BCA, ac);                                \
        ac = MF(AhC1, BCB, ac); ac = MF(AlC1, BCB, ac);                                \
        an = MF(AhN0, Bna, an); an = MF(AlN0, Bna, an);                                \
        an = MF(AhN1, Bnb, an); an = MF(AlN1, Bnb, an);                                \
        h2 c01 = lk2(pkrtz(ac[0], ac[1]) + u2h(cq.x));                                 \
        h2 c23 = lk2(pkrtz(ac[2], ac[3]) + u2h(cq.y));                                 \
        h2 n01 = lk2(pkrtz(an[0], an[1]) + u2h(nq.x));                                 \
        h2 n23 = lk2(pkrtz(an[2], an[3]) + u2h(nq.y));                                 \
        uint2 tv = { h2u(c01 * n01), h2u(c23 * n23) };                                 \
        *(uint2*)(thW + l15 * THROW + mt * 16 + g4) = tv;                              \
    }                                                                                  \
    { float v = spline_chunk(thW, xstS, widS + NT * 16, halfI, lane);                  \
      if (g == NT) logdet += v; }                                                      \
}

// ---------------- main kernel ----------------
extern "C" __global__ void __launch_bounds__(BLK, 2)
nsflow_main(const float* __restrict__ x_in, const float* __restrict__ xc_in,
            const f16* __restrict__ wsh, const f16* __restrict__ wsl,
            const uint32* __restrict__ wsbc, const uint32* __restrict__ wsbh,
            const float* __restrict__ wsWc,
            float* __restrict__ out){
    __shared__ float WcS[LLAYERS][DD][DD];
    __shared__ float ldcS;
    __shared__ f16 xstS[256 * XROW];
    __shared__ f16 actS[4 * 64 * 64];
    __shared__ f16 thS[4 * 16 * THROW];

    for (int e = threadIdx.x; e < 577; e += BLK){
        if (e < 576) ((float*)WcS)[e] = wsWc[e];
        else ldcS = wsWc[576];
    }

    int tid0 = threadIdx.x;
    int lane = tid0 & 63, wid = tid0 >> 6, widS = wid * 64;
    int l15 = lane & 15, g = lane >> 4, g4 = g * 4;
    int gsamp = blockIdx.x * BLK + tid0;

    float xr[DD];
    int xc0, xc1;
    {
        const float4* xv = (const float4*)(x_in + (size_t)gsamp * DD);
        float4 a0 = xv[0], a1 = xv[1], a2 = xv[2];
        xr[0]=a0.x; xr[1]=a0.y; xr[2]=a0.z; xr[3]=a0.w;
        xr[4]=a1.x; xr[5]=a1.y; xr[6]=a1.z; xr[7]=a1.w;
        xr[8]=a2.x; xr[9]=a2.y; xr[10]=a2.z; xr[11]=a2.w;
        float4 c0 = *(const float4*)(xc_in + (size_t)gsamp * 4);
        xc0 = (int)packh(c0.x, c0.y);
        xc1 = (int)packh(c0.z, c0.w);
    }
    __syncthreads();

    float logdet = ldcS;
    f16* actW = actS + wid * 4096;
    f16* thW = thS + wid * (16 * THROW);

#pragma unroll 1
    for (int l = 0; l < LLAYERS; ++l){
        if (l > 0){
            uint4 r0 = *(const uint4*)(xstS + tid0 * XROW);
            uint4 r1 = *(const uint4*)(xstS + tid0 * XROW + 8);
            xr[0]=unpl(r0.x); xr[1]=unph(r0.x); xr[2]=unpl(r0.y); xr[3]=unph(r0.y);
            xr[4]=unpl(r0.z); xr[5]=unph(r0.z);
            xr[6]=unpl(r1.x); xr[7]=unph(r1.x); xr[8]=unpl(r1.y); xr[9]=unph(r1.y);
            xr[10]=unpl(r1.z); xr[11]=unph(r1.z);
        }
        float xn[DD];
#pragma unroll
        for (int j = 0; j < DD; ++j) xn[j] = 0.f;
#pragma unroll
        for (int i = 0; i < DD; ++i){
            const float4* wr = (const float4*)WcS[l][i];
            float4 w0 = wr[0], w1 = wr[1], w2 = wr[2];
            float xi = xr[i];
            xn[0]=fmaf(xi,w0.x,xn[0]); xn[1]=fmaf(xi,w0.y,xn[1]); xn[2]=fmaf(xi,w0.z,xn[2]); xn[3]=fmaf(xi,w0.w,xn[3]);
            xn[4]=fmaf(xi,w1.x,xn[4]); xn[5]=fmaf(xi,w1.y,xn[5]); xn[6]=fmaf(xi,w1.z,xn[6]); xn[7]=fmaf(xi,w1.w,xn[7]);
            xn[8]=fmaf(xi,w2.x,xn[8]); xn[9]=fmaf(xi,w2.y,xn[9]); xn[10]=fmaf(xi,w2.z,xn[10]); xn[11]=fmaf(xi,w2.w,xn[11]);
        }
#pragma unroll
        for (int j = 0; j < DD; ++j) xr[j] = xn[j];
        // stage x: slots 0-5 = xr[0..5], 8-13 = xr[6..11]; slots 7,15 = 1.0 (bias-fold input)
        {
            uint4 s0 = { packh(xr[0],xr[1]), packh(xr[2],xr[3]), packh(xr[4],xr[5]), 0x3C000000u };
            uint4 s1 = { packh(xr[6],xr[7]), packh(xr[8],xr[9]), packh(xr[10],xr[11]), 0x3C000000u };
            *(uint4*)(xstS + tid0 * XROW) = s0;
            *(uint4*)(xstS + tid0 * XROW + 8) = s1;
        }

#pragma unroll 1
        for (int halfI = 0; halfI < 2; ++halfI){
            const f16* whC = wsh + (size_t)(l * 4 + halfI * 2) * NLW;
            const f16* wlC = wsl + (size_t)(l * 4 + halfI * 2) * NLW;
            const f16* whN = whC + NLW;
            const f16* wlN = wlC + NLW;
            const uint32* bhC = wsbh + (l * 4 + halfI * 2) * 64;
            const uint32* bhN = bhC + 64;
            const uint32* bcn = wsbc + (l * 2 + halfI) * 144;

            // conditioner chain
            gemmL0c(whC, wlC, xc0, xc1, actW, lane);
            gemm64(whC + WS_WH, wlC + WS_WH, bhC, actW, lane);
            gemm64(whC + WS_WH + 4096, wlC + WS_WH + 4096, bhC + 32, actW, lane);
            // snapshot conditioner final-hidden B fragments (32 VGPRs)
            f16x8 Bc0a = *actRd(actW,      l15, g * 16);
            f16x8 Bc0b = *actRd(actW,      l15, 64 + g * 16);
            f16x8 Bc1a = *actRd(actW, 16 + l15, g * 16);
            f16x8 Bc1b = *actRd(actW, 16 + l15, 64 + g * 16);
            f16x8 Bc2a = *actRd(actW, 32 + l15, g * 16);
            f16x8 Bc2b = *actRd(actW, 32 + l15, 64 + g * 16);
            f16x8 Bc3a = *actRd(actW, 48 + l15, g * 16);
            f16x8 Bc3b = *actRd(actW, 48 + l15, 64 + g * 16);

            // data chain (overwrites actW)
            gemmL0n(whN, wlN, xstS, halfI * 8, actW, lane, widS);
            gemm64(whN + WS_WH, wlN + WS_WH, bhN, actW, lane);
            gemm64(whN + WS_WH + 4096, wlN + WS_WH + 4096, bhN + 32, actW, lane);

            // fused finals + splines, one chunk at a time (th buffer = 16 rows)
            TAILP(0, Bc0a, Bc0b)
            TAILP(1, Bc1a, Bc1b)
            TAILP(2, Bc2a, Bc2b)
            TAILP(3, Bc3a, Bc3b)
        }
    }

    {
        uint4 r0 = *(const uint4*)(xstS + tid0 * XROW);
        uint4 r1 = *(const uint4*)(xstS + tid0 * XROW + 8);
        xr[0]=unpl(r0.x); xr[1]=unph(r0.x); xr[2]=unpl(r0.y); xr[3]=unph(r0.y);
        xr[4]=unpl(r0.z); xr[5]=unph(r0.z);
        xr[6]=unpl(r1.x); xr[7]=unph(r1.x); xr[8]=unpl(r1.y); xr[9]=unph(r1.y);
        xr[10]=unpl(r1.z); xr[11]=unph(r1.z);
    }
    float pr = 0.f;
#pragma unroll
    for (int j = 0; j < DD; ++j) pr = fmaf(-0.5f * xr[j], xr[j], pr);
    pr -= DD * 0.91893853320467274f;

    float4* ov = (float4*)(out + (size_t)gsamp * DD);
    ov[0] = make_float4(xr[0], xr[1], xr[2], xr[3]);
    ov[1] = make_float4(xr[4], xr[5], xr[6], xr[7]);
    ov[2] = make_float4(xr[8], xr[9], xr[10], xr[11]);
    out[(size_t)NSAMP * DD + gsamp] = logdet;
    out[(size_t)NSAMP * DD + NSAMP + gsamp] = pr;
}

extern "C" void kernel_launch(void* const* d_in, const int* in_sizes, int n_in,
                              void* d_out, int out_size, void* d_ws, size_t ws_size,
                              hipStream_t stream) {
    (void)in_sizes; (void)n_in; (void)out_size; (void)ws_size;
    const float* a[30];
    for (int i = 0; i < 30; ++i) a[i] = (const float*)d_in[i];
    f16* wsh = (f16*)d_ws;
    f16* wsl = wsh + 16 * NLW;
    uint32* wsbc = (uint32*)(wsl + 16 * NLW);   // 8*144 u32
    uint32* wsbh = wsbc + 8 * 144;              // 16*64 u32
    float* wsWc  = (float*)(wsbh + 16 * 64);    // 577 f32; total ws ≈ 1.16 MB

    dim3 pg(74, 16);
    nsflow_prep<<<pg, 256, 0, stream>>>(
        a[6], a[8], a[10], a[7], a[9], a[11],    // net1 W0,Wh,Wl,b0,bh,bl
        a[12], a[14], a[16], a[13], a[15], a[17],// net2
        a[18], a[20], a[22], a[19], a[21], a[23],// nc1
        a[24], a[26], a[28], a[25], a[27], a[29],// nc2
        a[2], a[3], a[4], a[5],                  // convP, convS, convL, convU
        wsh, wsl, wsbc, wsbh, wsWc);

    nsflow_main<<<NSAMP / BLK, BLK, 0, stream>>>(
        a[0], a[1], wsh, wsl, wsbc, wsbh, wsWc, (float*)d_out);
}

// Round 8
// 282.878 us; speedup vs baseline: 1.1929x; 1.1929x over previous
//
#include <hip/hip_runtime.h>
#include <math.h>

typedef _Float16 f16;
typedef _Float16 f16x8 __attribute__((ext_vector_type(8)));
typedef __fp16 h2 __attribute__((ext_vector_type(2)));
typedef float f32x4 __attribute__((ext_vector_type(4)));
typedef unsigned int uint32;
typedef unsigned short ushort16;

#define NSAMP 131072
#define DD 12
#define LLAYERS 4
#define KK 8
#define BV 3.0f
#define BLK 256
#define NLW 17920   // f16 elems per (net,layer): 512 (W0+b0) + 8192 (Wh) + 9216 (Wl)
#define WS_WH 512
#define WS_WL 8704
#define THROW 152   // th row: 152 f16 = 304 B (76 dw -> stride 12 mod 32, 2-way, aligned 16)
#define XROW 16     // xst row: 16 f16 = 32 B

__device__ __forceinline__ uint32 packh(float a, float b){
    union { f16 h; ushort16 u; } x, y;
    x.h = (f16)a; y.h = (f16)b;
    return (uint32)x.u | ((uint32)y.u << 16);
}
__device__ __forceinline__ float unpl(uint32 v){ union { ushort16 u; f16 h; } c; c.u = (ushort16)v; return (float)c.h; }
__device__ __forceinline__ float unph(uint32 v){ union { ushort16 u; f16 h; } c; c.u = (ushort16)(v >> 16); return (float)c.h; }

__device__ __forceinline__ h2 u2h(uint32 x){ union { uint32 u; h2 h; } c; c.u = x; return c.h; }
__device__ __forceinline__ uint32 h2u(h2 x){ union { h2 h; uint32 u; } c; c.h = x; return c.u; }
// leaky(x) = max(x, 0.2x) for slope<1 — no cmp/cndmask
__device__ __forceinline__ h2 lk2(h2 x){
    h2 k = { (__fp16)0.2f, (__fp16)0.2f };
    return __builtin_elementwise_max(x, x * k);
}
__device__ __forceinline__ h2 pkrtz(float a, float b){ return __builtin_amdgcn_cvt_pkrtz(a, b); }

__device__ __forceinline__ f32x4 MF(f16x8 a, f16x8 b, f32x4 c){
    return __builtin_amdgcn_mfma_f32_16x16x32_f16(a, b, c, 0, 0, 0);
}

// act tile: per-wave [64 samples][64 feats] f16, row=128B, XOR-swizzled by ((s&7)<<4)
__device__ __forceinline__ const f16x8* actRd(const f16* actW, int s, int fb){
    return (const f16x8*)((const char*)actW + s * 128 + (fb ^ ((s & 7) << 4)));
}
__device__ __forceinline__ uint2* actWr(f16* actW, int s, int fb){
    return (uint2*)((char*)actW + s * 128 + (fb ^ ((s & 7) << 4)));
}

// ---------------- prep: weights -> fp16 hi/lo fragments (final layer M-permuted to
// spline order m = dd*24+p); biases packed half2; conv W and logdet const ----------------
extern "C" __global__ void nsflow_prep(
        const float* __restrict__ n1W0, const float* __restrict__ n1Wh, const float* __restrict__ n1Wl,
        const float* __restrict__ n1b0, const float* __restrict__ n1bh, const float* __restrict__ n1bl,
        const float* __restrict__ n2W0, const float* __restrict__ n2Wh, const float* __restrict__ n2Wl,
        const float* __restrict__ n2b0, const float* __restrict__ n2bh, const float* __restrict__ n2bl,
        const float* __restrict__ c1W0, const float* __restrict__ c1Wh, const float* __restrict__ c1Wl,
        const float* __restrict__ c1b0, const float* __restrict__ c1bh, const float* __restrict__ c1bl,
        const float* __restrict__ c2W0, const float* __restrict__ c2Wh, const float* __restrict__ c2Wl,
        const float* __restrict__ c2b0, const float* __restrict__ c2bh, const float* __restrict__ c2bl,
        const float* __restrict__ convP, const float* __restrict__ convS,
        const float* __restrict__ convL, const float* __restrict__ convU,
        f16* __restrict__ ws_hi, f16* __restrict__ ws_lo,
        uint32* __restrict__ wsbc, uint32* __restrict__ wsbh, float* __restrict__ wsWc){
    int NL = blockIdx.y;                      // l*4 + net; net: 0=c1 1=n1 2=c2 3=n2
    int off = blockIdx.x * 256 + threadIdx.x;
    int layer = NL >> 2, net = NL & 3;

    const float *W0, *Wh, *Wl, *b0, *bh; int nin;
    if (net == 0){ W0 = c1W0; Wh = c1Wh; Wl = c1Wl; b0 = c1b0; bh = c1bh; nin = 4; }
    else if (net == 1){ W0 = n1W0; Wh = n1Wh; Wl = n1Wl; b0 = n1b0; bh = n1bh; nin = 6; }
    else if (net == 2){ W0 = c2W0; Wh = c2Wh; Wl = c2Wl; b0 = c2b0; bh = c2bh; nin = 4; }
    else { W0 = n2W0; Wh = n2Wh; Wl = n2Wl; b0 = n2b0; bh = n2bh; nin = 6; }

    if (off < 17920){
        float w = 0.f;
        if (off < 512){                          // W0^T frags: [mt(4)][16 lanes][8 j]; j==7 -> bias
            int mt = off >> 7, r = off & 127, ln = r >> 3, j = r & 7;
            int row = mt * 16 + ln;
            if (j < nin) w = W0[(layer * nin + j) * 64 + row];
            else if (j == 7) w = b0[layer * 64 + row];
        } else if (off < 8704){                  // Wh^T frags: [h(2)][mt*2+ks (8)][64 lanes][8 j]
            int o = off - 512; int h = o >> 12; o &= 4095;
            int t = o >> 9, ln = (o >> 3) & 63, j = o & 7;
            int mt = t >> 1, ks = t & 1;
            int k = ks * 32 + (ln >> 4) * 8 + j, row = mt * 16 + (ln & 15);
            w = Wh[((layer * 2 + h) * 64 + k) * 64 + row];
        } else {                                 // Wl^T frags, M-permuted: m = dd*24+p -> f = dd*23+p
            int o = off - 8704;
            int t = o >> 9, ln = (o >> 3) & 63, j = o & 7;
            int mt = t >> 1, ks = t & 1;
            int k = ks * 32 + (ln >> 4) * 8 + j, m = mt * 16 + (ln & 15);
            int dd = m / 24, p = m - dd * 24;
            if (p < 23) w = Wl[(layer * 64 + k) * 138 + dd * 23 + p];
        }
        f16 hi = (f16)w;
        f16 lo = (f16)(w - (float)hi);
        ws_hi[NL * NLW + off] = hi;
        ws_lo[NL * NLW + off] = lo;
    } else if (off < 18064){                     // final-layer bias half2 pairs (cond [0..71], net [72..143])
        int mm = off - 17920;
        if (net == 0 || net == 2){
            int halfI = net >> 1;
            int s = layer * 2 + halfI;
            bool isn = mm >= 72;
            int m0 = 2 * (isn ? mm - 72 : mm);
            const float* bb = isn ? (halfI ? n2bl : n1bl) : (halfI ? c2bl : c1bl);
            int dd0 = m0 / 24, p0 = m0 - dd0 * 24;
            int m1 = m0 + 1;
            int dd1 = m1 / 24, p1 = m1 - dd1 * 24;
            float v0 = (p0 < 23) ? bb[layer * 138 + dd0 * 23 + p0] : 0.f;
            float v1 = (p1 < 23) ? bb[layer * 138 + dd1 * 23 + p1] : 0.f;
            wsbc[s * 144 + mm] = packh(v0, v1);
        }
    } else if (off < 18128){                     // hidden bias half2 pairs: [NL][h(2)][32]
        int q = off - 18064;
        int h = q >> 5, r = q & 31, m0 = 2 * r;
        wsbh[NL * 64 + q] = packh(bh[(layer * 2 + h) * 64 + m0], bh[(layer * 2 + h) * 64 + m0 + 1]);
    } else if (off < 18705 && NL == 0){          // conv W = P(L+I)(U+diag(S)) and logdet const
        int idx = off - 18128;
        if (idx < 576){
            int l = idx / 144, r = idx - l * 144;
            int i = r / 12, j = r - i * 12;
            const float* P = convP + l * 144;
            const float* Lm = convL + l * 144;
            const float* Um = convU + l * 144;
            const float* Sv = convS + l * 12;
            float acc = 0.f;
            for (int a = 0; a < 12; ++a){
                float inner = 0.f;
                for (int bb2 = 0; bb2 < 12; ++bb2){
                    float m1 = (bb2 < a) ? Lm[a * 12 + bb2] : (bb2 == a ? 1.f : 0.f);
                    float m2 = (j > bb2) ? Um[bb2 * 12 + j] : (j == bb2 ? Sv[j] : 0.f);
                    inner = fmaf(m1, m2, inner);
                }
                acc = fmaf(P[i * 12 + a], inner, acc);
            }
            wsWc[idx] = acc;
        } else if (idx == 576){
            float sacc = 0.f;
            for (int q2 = 0; q2 < LLAYERS * 12; ++q2) sacc += __logf(fabsf(convS[q2]));
            wsWc[576] = sacc;
        }
    }
}

// ---------------- GEMM helpers ----------------
// first layer, conditioner: B built by shuffle from per-thread xc regs; bias folded (B slot7=1)
__device__ __forceinline__ void gemmL0c(const f16* __restrict__ ah, const f16* __restrict__ al,
                                        int xc0, int xc1, f16* actW, int lane){
    int l15 = lane & 15, g = lane >> 4;
    f16x8 Z = {};
    f16x8 Bf[4];
#pragma unroll
    for (int nt = 0; nt < 4; ++nt){
        union { uint4 u; f16x8 v; } cc;
        cc.u.x = (uint32)__shfl(xc0, nt * 16 + l15, 64);
        cc.u.y = (uint32)__shfl(xc1, nt * 16 + l15, 64);
        cc.u.z = 0u;
        cc.u.w = 0x3C000000u;   // slots 6,7 = (0, 1.0h)
        Bf[nt] = cc.v;
    }
    bool g0 = (g == 0);
#pragma unroll
    for (int mt = 0; mt < 4; ++mt){
        f16x8 Ah = g0 ? *(const f16x8*)(ah + (mt * 16 + l15) * 8) : Z;
        f16x8 Al = g0 ? *(const f16x8*)(al + (mt * 16 + l15) * 8) : Z;
#pragma unroll
        for (int nt = 0; nt < 4; ++nt){
            f32x4 acc = {0.f, 0.f, 0.f, 0.f};
            acc = MF(Ah, Bf[nt], acc);
            acc = MF(Al, Bf[nt], acc);
            uint2 v = { h2u(lk2(pkrtz(acc[0], acc[1]))), h2u(lk2(pkrtz(acc[2], acc[3]))) };
            *actWr(actW, nt * 16 + l15, mt * 32 + g * 8) = v;
        }
    }
}

// first layer, data net: B from xstS rows (bias folded, slot 7/15 = 1.0)
__device__ __forceinline__ void gemmL0n(const f16* __restrict__ ah, const f16* __restrict__ al,
                                        const f16* src, int offE,
                                        f16* actW, int lane, int widS){
    int l15 = lane & 15, g = lane >> 4;
    f16x8 Z = {};
    f16x8 Bf[4];
#pragma unroll
    for (int nt = 0; nt < 4; ++nt)
        Bf[nt] = *(const f16x8*)(src + (widS + nt * 16 + l15) * XROW + offE);
    bool g0 = (g == 0);
#pragma unroll
    for (int mt = 0; mt < 4; ++mt){
        f16x8 Ah = g0 ? *(const f16x8*)(ah + (mt * 16 + l15) * 8) : Z;
        f16x8 Al = g0 ? *(const f16x8*)(al + (mt * 16 + l15) * 8) : Z;
#pragma unroll
        for (int nt = 0; nt < 4; ++nt){
            f32x4 acc = {0.f, 0.f, 0.f, 0.f};
            acc = MF(Ah, Bf[nt], acc);
            acc = MF(Al, Bf[nt], acc);
            uint2 v = { h2u(lk2(pkrtz(acc[0], acc[1]))), h2u(lk2(pkrtz(acc[2], acc[3]))) };
            *actWr(actW, nt * 16 + l15, mt * 32 + g * 8) = v;
        }
    }
}

// hidden 64->64, in place; bias as packed half2 pairs (32 u32 per layer-half)
__device__ __forceinline__ void gemm64(const f16* __restrict__ ah, const f16* __restrict__ al,
                                       const uint32* __restrict__ bq,
                                       f16* actW, int lane){
    int l15 = lane & 15, g = lane >> 4;
    f16x8 Bf[4][2];
#pragma unroll
    for (int nt = 0; nt < 4; ++nt)
#pragma unroll
        for (int ks = 0; ks < 2; ++ks)
            Bf[nt][ks] = *actRd(actW, nt * 16 + l15, ks * 64 + g * 16);
#pragma unroll
    for (int mt = 0; mt < 4; ++mt){
        f16x8 Ah0 = *(const f16x8*)(ah + ((mt * 2 + 0) * 64 + lane) * 8);
        f16x8 Ah1 = *(const f16x8*)(ah + ((mt * 2 + 1) * 64 + lane) * 8);
        f16x8 Al0 = *(const f16x8*)(al + ((mt * 2 + 0) * 64 + lane) * 8);
        f16x8 Al1 = *(const f16x8*)(al + ((mt * 2 + 1) * 64 + lane) * 8);
        uint2 bp = *(const uint2*)(bq + mt * 8 + g * 2);
#pragma unroll
        for (int nt = 0; nt < 4; ++nt){
            f32x4 acc = {0.f, 0.f, 0.f, 0.f};
            acc = MF(Ah0, Bf[nt][0], acc);
            acc = MF(Al0, Bf[nt][0], acc);
            acc = MF(Ah1, Bf[nt][1], acc);
            acc = MF(Al1, Bf[nt][1], acc);
            uint2 v = { h2u(lk2(pkrtz(acc[0], acc[1]) + u2h(bp.x))),
                        h2u(lk2(pkrtz(acc[2], acc[3]) + u2h(bp.y))) };
            *actWr(actW, nt * 16 + l15, mt * 32 + g * 8) = v;
        }
    }
}

// spline for one chunk of 16 samples; lane L ends with 6-dim logdet sum for sample sbase+(L&15)
__device__ __forceinline__ float spline_chunk(const f16* thW, f16* xst,
                                              int sbase, int halfI, int lane){
    float vsum = 0.f;
#pragma unroll 1
    for (int pass = 0; pass < 2; ++pass){
        if (pass == 1 && lane >= 32) break;
        int dd = pass * 4 + (lane >> 4);
        int s16 = lane & 15;

        const f16* tr = thW + s16 * THROW + dd * 24;
        f16x8 t0 = *(const f16x8*)(tr);
        f16x8 t1 = *(const f16x8*)(tr + 8);
        f16x8 t2 = *(const f16x8*)(tr + 16);
        float th[23];
#pragma unroll
        for (int j = 0; j < 8; ++j) th[j] = (float)t0[j];
#pragma unroll
        for (int j = 0; j < 8; ++j) th[8 + j] = (float)t1[j];
#pragma unroll
        for (int j = 0; j < 7; ++j) th[16 + j] = (float)t2[j];

        float mw = th[0];
#pragma unroll
        for (int j = 1; j < KK; ++j) mw = fmaxf(mw, th[j]);
        float ew[KK]; float swsum = 0.f;
#pragma unroll
        for (int j = 0; j < KK; ++j){ ew[j] = __expf(th[j] - mw); swsum += ew[j]; }
        float iw_ = 6.0f / swsum;
        float mh = th[KK];
#pragma unroll
        for (int j = 1; j < KK; ++j) mh = fmaxf(mh, th[KK + j]);
        float eh[KK]; float shsum = 0.f;
#pragma unroll
        for (int j = 0; j < KK; ++j){ eh[j] = __expf(th[KK + j] - mh); shsum += eh[j]; }
        float ih_ = 6.0f / shsum;
        float dv[KK + 1];
        dv[0] = 1.0f; dv[KK] = 1.0f;
#pragma unroll
        for (int j = 0; j < KK - 1; ++j){
            float v = th[2 * KK + j];
            float z = __expf(-fabsf(v));
            dv[j + 1] = fmaxf(v, 0.f) + __logf(1.0f + z);
        }

        int sidx = sbase + s16;
        int slot = halfI ? dd : 8 + dd;
        float X = (float)xst[sidx * XROW + slot];
        float Xc = fminf(fmaxf(X, -BV), BV);

        float cx = -BV, cy = -BV;
        float xk = -BV, xk1 = BV, yk = -BV, yk1 = BV, dk = 1.0f, dk1 = 1.0f;
#pragma unroll
        for (int j = 0; j < KK; ++j){
            float nx = (j == KK - 1) ? (BV + 1e-6f) : (cx + ew[j] * iw_);
            float ny = (j == KK - 1) ? BV : (cy + eh[j] * ih_);
            bool sel = (j == 0) || (Xc >= cx);
            if (sel){ xk = cx; xk1 = nx; yk = cy; yk1 = ny; dk = dv[j]; dk1 = dv[j + 1]; }
            cx = nx; cy = ny;
        }
        float idx_ = 1.0f / (xk1 - xk);
        float s_ = (yk1 - yk) * idx_;
        float xi = (Xc - xk) * idx_;
        float om = 1.0f - xi;
        float xo = xi * om;
        float den = s_ + (dk1 + dk - 2.0f * s_) * xo;
        float Y = yk + (yk1 - yk) * (s_ * xi * xi + dk * xo) / den;
        float dydx = s_ * s_ * (dk1 * xi * xi + 2.0f * s_ * xo + dk * om * om) / (den * den);
        bool inside = (X <= BV) && (X >= -BV);
        float Yo = inside ? Y : X;
        float ldv = inside ? __logf(dydx) : 0.f;
        xst[sidx * XROW + slot] = (f16)Yo;
        vsum += ldv;
    }
    vsum += __shfl_xor(vsum, 16, 64);
    vsum += __shfl_xor(vsum, 32, 64);
    return vsum;
}

// paired tail: chunks NT0,NT1 share the per-mt A-fragment loads (halves final-layer L2
// traffic vs single-chunk — R7 post-mortem). th buffer = 32 rows (NT0 -> 0-15, NT1 -> 16-31).
#define TAILP(NT0, NT1, BC0A, BC0B, BC1A, BC1B)                                        \
{                                                                                      \
    f16x8 Bn0a = *actRd(actW, NT0 * 16 + l15, g * 16);                                 \
    f16x8 Bn0b = *actRd(actW, NT0 * 16 + l15, 64 + g * 16);                            \
    f16x8 Bn1a = *actRd(actW, NT1 * 16 + l15, g * 16);                                 \
    f16x8 Bn1b = *actRd(actW, NT1 * 16 + l15, 64 + g * 16);                            \
    _Pragma("unroll")                                                                  \
    for (int mt = 0; mt < 9; ++mt){                                                    \
        const f16* pch = whC + WS_WL + (mt * 128 + lane) * 8;                          \
        const f16* pcl = wlC + WS_WL + (mt * 128 + lane) * 8;                          \
        const f16* pnh = whN + WS_WL + (mt * 128 + lane) * 8;                          \
        const f16* pnl = wlN + WS_WL + (mt * 128 + lane) * 8;                          \
        f16x8 AhC0 = *(const f16x8*)(pch);                                             \
        f16x8 AhC1 = *(const f16x8*)(pch + 512);                                       \
        f16x8 AlC0 = *(const f16x8*)(pcl);                                             \
        f16x8 AlC1 = *(const f16x8*)(pcl + 512);                                       \
        f16x8 AhN0 = *(const f16x8*)(pnh);                                             \
        f16x8 AhN1 = *(const f16x8*)(pnh + 512);                                       \
        f16x8 AlN0 = *(const f16x8*)(pnl);                                             \
        f16x8 AlN1 = *(const f16x8*)(pnl + 512);                                       \
        uint2 cq = *(const uint2*)(bcn + mt * 8 + g * 2);                              \
        uint2 nq = *(const uint2*)(bcn + 72 + mt * 8 + g * 2);                         \
        f32x4 ac = {0.f,0.f,0.f,0.f}, an = {0.f,0.f,0.f,0.f};                          \
        ac = MF(AhC0, BC0A, ac); ac = MF(AlC0, BC0A, ac);                              \
        ac = MF(AhC1, BC0B, ac); ac = MF(AlC1, BC0B, ac);                              \
        an = MF(AhN0, Bn0a, an); an = MF(AlN0, Bn0a, an);                              \
        an = MF(AhN1, Bn0b, an); an = MF(AlN1, Bn0b, an);                              \
        h2 c01 = lk2(pkrtz(ac[0], ac[1]) + u2h(cq.x));                                 \
        h2 c23 = lk2(pkrtz(ac[2], ac[3]) + u2h(cq.y));                                 \
        h2 n01 = lk2(pkrtz(an[0], an[1]) + u2h(nq.x));                                 \
        h2 n23 = lk2(pkrtz(an[2], an[3]) + u2h(nq.y));                                 \
        uint2 tv0 = { h2u(c01 * n01), h2u(c23 * n23) };                                \
        *(uint2*)(thW + l15 * THROW + mt * 16 + g4) = tv0;                             \
        f32x4 ac2 = {0.f,0.f,0.f,0.f}, an2 = {0.f,0.f,0.f,0.f};                        \
        ac2 = MF(AhC0, BC1A, ac2); ac2 = MF(AlC0, BC1A, ac2);                          \
        ac2 = MF(AhC1, BC1B, ac2); ac2 = MF(AlC1, BC1B, ac2);                          \
        an2 = MF(AhN0, Bn1a, an2); an2 = MF(AlN0, Bn1a, an2);                          \
        an2 = MF(AhN1, Bn1b, an2); an2 = MF(AlN1, Bn1b, an2);                          \
        h2 d01 = lk2(pkrtz(ac2[0], ac2[1]) + u2h(cq.x));                               \
        h2 d23 = lk2(pkrtz(ac2[2], ac2[3]) + u2h(cq.y));                               \
        h2 m01 = lk2(pkrtz(an2[0], an2[1]) + u2h(nq.x));                               \
        h2 m23 = lk2(pkrtz(an2[2], an2[3]) + u2h(nq.y));                               \
        uint2 tv1 = { h2u(d01 * m01), h2u(d23 * m23) };                                \
        *(uint2*)(thW + (16 + l15) * THROW + mt * 16 + g4) = tv1;                      \
    }                                                                                  \
    { float v = spline_chunk(thW, xstS, widS + NT0 * 16, halfI, lane);                 \
      if (g == NT0) logdet += v; }                                                     \
    { float v = spline_chunk(thW + 16 * THROW, xstS, widS + NT1 * 16, halfI, lane);    \
      if (g == NT1) logdet += v; }                                                     \
}

// ---------------- main kernel ----------------
extern "C" __global__ void __launch_bounds__(BLK, 2)
nsflow_main(const float* __restrict__ x_in, const float* __restrict__ xc_in,
            const f16* __restrict__ wsh, const f16* __restrict__ wsl,
            const uint32* __restrict__ wsbc, const uint32* __restrict__ wsbh,
            const float* __restrict__ wsWc,
            float* __restrict__ out){
    __shared__ f16 xstS[256 * XROW];
    __shared__ f16 actS[4 * 64 * 64];
    __shared__ f16 thS[4 * 32 * THROW];

    int tid0 = threadIdx.x;
    int lane = tid0 & 63, wid = tid0 >> 6, widS = wid * 64;
    int l15 = lane & 15, g = lane >> 4, g4 = g * 4;
    int gsamp = blockIdx.x * BLK + tid0;

    float xr[DD];
    int xc0, xc1;
    {
        const float4* xv = (const float4*)(x_in + (size_t)gsamp * DD);
        float4 a0 = xv[0], a1 = xv[1], a2 = xv[2];
        xr[0]=a0.x; xr[1]=a0.y; xr[2]=a0.z; xr[3]=a0.w;
        xr[4]=a1.x; xr[5]=a1.y; xr[6]=a1.z; xr[7]=a1.w;
        xr[8]=a2.x; xr[9]=a2.y; xr[10]=a2.z; xr[11]=a2.w;
        float4 c0 = *(const float4*)(xc_in + (size_t)gsamp * 4);
        xc0 = (int)packh(c0.x, c0.y);
        xc1 = (int)packh(c0.z, c0.w);
    }

    float logdet = wsWc[576];   // conv logdet const (uniform -> s_load)
    f16* actW = actS + wid * 4096;
    f16* thW = thS + wid * (32 * THROW);

#pragma unroll 1
    for (int l = 0; l < LLAYERS; ++l){
        if (l > 0){
            uint4 r0 = *(const uint4*)(xstS + tid0 * XROW);
            uint4 r1 = *(const uint4*)(xstS + tid0 * XROW + 8);
            xr[0]=unpl(r0.x); xr[1]=unph(r0.x); xr[2]=unpl(r0.y); xr[3]=unph(r0.y);
            xr[4]=unpl(r0.z); xr[5]=unph(r0.z);
            xr[6]=unpl(r1.x); xr[7]=unph(r1.x); xr[8]=unpl(r1.y); xr[9]=unph(r1.y);
            xr[10]=unpl(r1.z); xr[11]=unph(r1.z);
        }
        // x = x @ Wconv[l], W rows read uniform from global (s_load, no LDS)
        float xn[DD];
#pragma unroll
        for (int j = 0; j < DD; ++j) xn[j] = 0.f;
#pragma unroll
        for (int i = 0; i < DD; ++i){
            const float4* wr = (const float4*)(wsWc + l * 144 + i * 12);
            float4 w0 = wr[0], w1 = wr[1], w2 = wr[2];
            float xi = xr[i];
            xn[0]=fmaf(xi,w0.x,xn[0]); xn[1]=fmaf(xi,w0.y,xn[1]); xn[2]=fmaf(xi,w0.z,xn[2]); xn[3]=fmaf(xi,w0.w,xn[3]);
            xn[4]=fmaf(xi,w1.x,xn[4]); xn[5]=fmaf(xi,w1.y,xn[5]); xn[6]=fmaf(xi,w1.z,xn[6]); xn[7]=fmaf(xi,w1.w,xn[7]);
            xn[8]=fmaf(xi,w2.x,xn[8]); xn[9]=fmaf(xi,w2.y,xn[9]); xn[10]=fmaf(xi,w2.z,xn[10]); xn[11]=fmaf(xi,w2.w,xn[11]);
        }
#pragma unroll
        for (int j = 0; j < DD; ++j) xr[j] = xn[j];
        // stage x: slots 0-5 = xr[0..5], 8-13 = xr[6..11]; slots 7,15 = 1.0 (bias-fold input)
        {
            uint4 s0 = { packh(xr[0],xr[1]), packh(xr[2],xr[3]), packh(xr[4],xr[5]), 0x3C000000u };
            uint4 s1 = { packh(xr[6],xr[7]), packh(xr[8],xr[9]), packh(xr[10],xr[11]), 0x3C000000u };
            *(uint4*)(xstS + tid0 * XROW) = s0;
            *(uint4*)(xstS + tid0 * XROW + 8) = s1;
        }

#pragma unroll 1
        for (int halfI = 0; halfI < 2; ++halfI){
            const f16* whC = wsh + (size_t)(l * 4 + halfI * 2) * NLW;
            const f16* wlC = wsl + (size_t)(l * 4 + halfI * 2) * NLW;
            const f16* whN = whC + NLW;
            const f16* wlN = wlC + NLW;
            const uint32* bhC = wsbh + (l * 4 + halfI * 2) * 64;
            const uint32* bhN = bhC + 64;
            const uint32* bcn = wsbc + (l * 2 + halfI) * 144;

            // conditioner chain
            gemmL0c(whC, wlC, xc0, xc1, actW, lane);
            gemm64(whC + WS_WH, wlC + WS_WH, bhC, actW, lane);
            gemm64(whC + WS_WH + 4096, wlC + WS_WH + 4096, bhC + 32, actW, lane);
            // snapshot conditioner final-hidden B fragments (32 VGPRs)
            f16x8 Bc0a = *actRd(actW,      l15, g * 16);
            f16x8 Bc0b = *actRd(actW,      l15, 64 + g * 16);
            f16x8 Bc1a = *actRd(actW, 16 + l15, g * 16);
            f16x8 Bc1b = *actRd(actW, 16 + l15, 64 + g * 16);
            f16x8 Bc2a = *actRd(actW, 32 + l15, g * 16);
            f16x8 Bc2b = *actRd(actW, 32 + l15, 64 + g * 16);
            f16x8 Bc3a = *actRd(actW, 48 + l15, g * 16);
            f16x8 Bc3b = *actRd(actW, 48 + l15, 64 + g * 16);

            // data chain (overwrites actW)
            gemmL0n(whN, wlN, xstS, halfI * 8, actW, lane, widS);
            gemm64(whN + WS_WH, wlN + WS_WH, bhN, actW, lane);
            gemm64(whN + WS_WH + 4096, wlN + WS_WH + 4096, bhN + 32, actW, lane);

            // fused finals + splines, paired chunks sharing A-fragment loads
            TAILP(0, 1, Bc0a, Bc0b, Bc1a, Bc1b)
            TAILP(2, 3, Bc2a, Bc2b, Bc3a, Bc3b)
        }
    }

    {
        uint4 r0 = *(const uint4*)(xstS + tid0 * XROW);
        uint4 r1 = *(const uint4*)(xstS + tid0 * XROW + 8);
        xr[0]=unpl(r0.x); xr[1]=unph(r0.x); xr[2]=unpl(r0.y); xr[3]=unph(r0.y);
        xr[4]=unpl(r0.z); xr[5]=unph(r0.z);
        xr[6]=unpl(r1.x); xr[7]=unph(r1.x); xr[8]=unpl(r1.y); xr[9]=unph(r1.y);
        xr[10]=unpl(r1.z); xr[11]=unph(r1.z);
    }
    float pr = 0.f;
#pragma unroll
    for (int j = 0; j < DD; ++j) pr = fmaf(-0.5f * xr[j], xr[j], pr);
    pr -= DD * 0.91893853320467274f;

    float4* ov = (float4*)(out + (size_t)gsamp * DD);
    ov[0] = make_float4(xr[0], xr[1], xr[2], xr[3]);
    ov[1] = make_float4(xr[4], xr[5], xr[6], xr[7]);
    ov[2] = make_float4(xr[8], xr[9], xr[10], xr[11]);
    out[(size_t)NSAMP * DD + gsamp] = logdet;
    out[(size_t)NSAMP * DD + NSAMP + gsamp] = pr;
}

extern "C" void kernel_launch(void* const* d_in, const int* in_sizes, int n_in,
                              void* d_out, int out_size, void* d_ws, size_t ws_size,
                              hipStream_t stream) {
    (void)in_sizes; (void)n_in; (void)out_size; (void)ws_size;
    const float* a[30];
    for (int i = 0; i < 30; ++i) a[i] = (const float*)d_in[i];
    f16* wsh = (f16*)d_ws;
    f16* wsl = wsh + 16 * NLW;
    uint32* wsbc = (uint32*)(wsl + 16 * NLW);   // 8*144 u32
    uint32* wsbh = wsbc + 8 * 144;              // 16*64 u32
    float* wsWc  = (float*)(wsbh + 16 * 64);    // 577 f32; total ws ≈ 1.16 MB

    dim3 pg(74, 16);
    nsflow_prep<<<pg, 256, 0, stream>>>(
        a[6], a[8], a[10], a[7], a[9], a[11],    // net1 W0,Wh,Wl,b0,bh,bl
        a[12], a[14], a[16], a[13], a[15], a[17],// net2
        a[18], a[20], a[22], a[19], a[21], a[23],// nc1
        a[24], a[26], a[28], a[25], a[27], a[29],// nc2
        a[2], a[3], a[4], a[5],                  // convP, convS, convL, convU
        wsh, wsl, wsbc, wsbh, wsWc);

    nsflow_main<<<NSAMP / BLK, BLK, 0, stream>>>(
        a[0], a[1], wsh, wsl, wsbc, wsbh, wsWc, (float*)d_out);
}

// Round 9
// 229.537 us; speedup vs baseline: 1.4701x; 1.2324x over previous
//
#include <hip/hip_runtime.h>
#include <math.h>

typedef _Float16 f16;
typedef _Float16 f16x8 __attribute__((ext_vector_type(8)));
typedef __fp16 h2 __attribute__((ext_vector_type(2)));
typedef float f32x4 __attribute__((ext_vector_type(4)));
typedef unsigned int uint32;
typedef unsigned short ushort16;

#define NSAMP 131072
#define DD 12
#define LLAYERS 4
#define KK 8
#define BV 3.0f
#define BLK 256
#define NLW 17920   // f16 elems per (net,layer): 512 (W0+b0) + 8192 (Wh) + 9216 (Wl)
#define WS_WH 512
#define WS_WL 8704
#define THROW 152   // th row: 152 f16 = 304 B
#define XROW 16     // xst row: 16 f16 = 32 B
#define SENTD 0.54132485f  // softplus(SENTD) = 1.0 — endpoint-derivative sentinel

__device__ __forceinline__ uint32 packh(float a, float b){
    union { f16 h; ushort16 u; } x, y;
    x.h = (f16)a; y.h = (f16)b;
    return (uint32)x.u | ((uint32)y.u << 16);
}
__device__ __forceinline__ float unpl(uint32 v){ union { ushort16 u; f16 h; } c; c.u = (ushort16)v; return (float)c.h; }
__device__ __forceinline__ float unph(uint32 v){ union { ushort16 u; f16 h; } c; c.u = (ushort16)(v >> 16); return (float)c.h; }

__device__ __forceinline__ h2 u2h(uint32 x){ union { uint32 u; h2 h; } c; c.u = x; return c.h; }
__device__ __forceinline__ uint32 h2u(h2 x){ union { h2 h; uint32 u; } c; c.h = x; return c.u; }
// leaky(x) = max(x, 0.2x) for slope<1 — no cmp/cndmask
__device__ __forceinline__ h2 lk2(h2 x){
    h2 k = { (__fp16)0.2f, (__fp16)0.2f };
    return __builtin_elementwise_max(x, x * k);
}
__device__ __forceinline__ h2 pkrtz(float a, float b){ return __builtin_amdgcn_cvt_pkrtz(a, b); }

__device__ __forceinline__ f32x4 MF(f16x8 a, f16x8 b, f32x4 c){
    return __builtin_amdgcn_mfma_f32_16x16x32_f16(a, b, c, 0, 0, 0);
}

// act tile: per-wave [64 samples][64 feats] f16, row=128B, XOR-swizzled by ((s&7)<<4)
__device__ __forceinline__ const f16x8* actRd(const f16* actW, int s, int fb){
    return (const f16x8*)((const char*)actW + s * 128 + (fb ^ ((s & 7) << 4)));
}
__device__ __forceinline__ uint2* actWr(f16* actW, int s, int fb){
    return (uint2*)((char*)actW + s * 128 + (fb ^ ((s & 7) << 4)));
}

// ---------------- prep: weights -> fp16 hi/lo fragments (final layer M-permuted to
// spline order m = dd*24+p); biases packed half2; conv W and logdet const ----------------
extern "C" __global__ void nsflow_prep(
        const float* __restrict__ n1W0, const float* __restrict__ n1Wh, const float* __restrict__ n1Wl,
        const float* __restrict__ n1b0, const float* __restrict__ n1bh, const float* __restrict__ n1bl,
        const float* __restrict__ n2W0, const float* __restrict__ n2Wh, const float* __restrict__ n2Wl,
        const float* __restrict__ n2b0, const float* __restrict__ n2bh, const float* __restrict__ n2bl,
        const float* __restrict__ c1W0, const float* __restrict__ c1Wh, const float* __restrict__ c1Wl,
        const float* __restrict__ c1b0, const float* __restrict__ c1bh, const float* __restrict__ c1bl,
        const float* __restrict__ c2W0, const float* __restrict__ c2Wh, const float* __restrict__ c2Wl,
        const float* __restrict__ c2b0, const float* __restrict__ c2bh, const float* __restrict__ c2bl,
        const float* __restrict__ convP, const float* __restrict__ convS,
        const float* __restrict__ convL, const float* __restrict__ convU,
        f16* __restrict__ ws_hi, f16* __restrict__ ws_lo,
        uint32* __restrict__ wsbc, uint32* __restrict__ wsbh, float* __restrict__ wsWc){
    int NL = blockIdx.y;                      // l*4 + net; net: 0=c1 1=n1 2=c2 3=n2
    int off = blockIdx.x * 256 + threadIdx.x;
    int layer = NL >> 2, net = NL & 3;

    const float *W0, *Wh, *Wl, *b0, *bh; int nin;
    if (net == 0){ W0 = c1W0; Wh = c1Wh; Wl = c1Wl; b0 = c1b0; bh = c1bh; nin = 4; }
    else if (net == 1){ W0 = n1W0; Wh = n1Wh; Wl = n1Wl; b0 = n1b0; bh = n1bh; nin = 6; }
    else if (net == 2){ W0 = c2W0; Wh = c2Wh; Wl = c2Wl; b0 = c2b0; bh = c2bh; nin = 4; }
    else { W0 = n2W0; Wh = n2Wh; Wl = n2Wl; b0 = n2b0; bh = n2bh; nin = 6; }

    if (off < 17920){
        float w = 0.f;
        if (off < 512){                          // W0^T frags: [mt(4)][16 lanes][8 j]; j==7 -> bias
            int mt = off >> 7, r = off & 127, ln = r >> 3, j = r & 7;
            int row = mt * 16 + ln;
            if (j < nin) w = W0[(layer * nin + j) * 64 + row];
            else if (j == 7) w = b0[layer * 64 + row];
        } else if (off < 8704){                  // Wh^T frags: [h(2)][mt*2+ks (8)][64 lanes][8 j]
            int o = off - 512; int h = o >> 12; o &= 4095;
            int t = o >> 9, ln = (o >> 3) & 63, j = o & 7;
            int mt = t >> 1, ks = t & 1;
            int k = ks * 32 + (ln >> 4) * 8 + j, row = mt * 16 + (ln & 15);
            w = Wh[((layer * 2 + h) * 64 + k) * 64 + row];
        } else {                                 // Wl^T frags, M-permuted: m = dd*24+p -> f = dd*23+p
            int o = off - 8704;
            int t = o >> 9, ln = (o >> 3) & 63, j = o & 7;
            int mt = t >> 1, ks = t & 1;
            int k = ks * 32 + (ln >> 4) * 8 + j, m = mt * 16 + (ln & 15);
            int dd = m / 24, p = m - dd * 24;
            if (p < 23) w = Wl[(layer * 64 + k) * 138 + dd * 23 + p];
        }
        f16 hi = (f16)w;
        f16 lo = (f16)(w - (float)hi);
        ws_hi[NL * NLW + off] = hi;
        ws_lo[NL * NLW + off] = lo;
    } else if (off < 18064){                     // final-layer bias half2 pairs (cond [0..71], net [72..143])
        int mm = off - 17920;
        if (net == 0 || net == 2){
            int halfI = net >> 1;
            int s = layer * 2 + halfI;
            bool isn = mm >= 72;
            int m0 = 2 * (isn ? mm - 72 : mm);
            const float* bb = isn ? (halfI ? n2bl : n1bl) : (halfI ? c2bl : c1bl);
            int dd0 = m0 / 24, p0 = m0 - dd0 * 24;
            int m1 = m0 + 1;
            int dd1 = m1 / 24, p1 = m1 - dd1 * 24;
            float v0 = (p0 < 23) ? bb[layer * 138 + dd0 * 23 + p0] : 0.f;
            float v1 = (p1 < 23) ? bb[layer * 138 + dd1 * 23 + p1] : 0.f;
            wsbc[s * 144 + mm] = packh(v0, v1);
        }
    } else if (off < 18128){                     // hidden bias half2 pairs: [NL][h(2)][32]
        int q = off - 18064;
        int h = q >> 5, r = q & 31, m0 = 2 * r;
        wsbh[NL * 64 + q] = packh(bh[(layer * 2 + h) * 64 + m0], bh[(layer * 2 + h) * 64 + m0 + 1]);
    } else if (off < 18705 && NL == 0){          // conv W = P(L+I)(U+diag(S)) and logdet const
        int idx = off - 18128;
        if (idx < 576){
            int l = idx / 144, r = idx - l * 144;
            int i = r / 12, j = r - i * 12;
            const float* P = convP + l * 144;
            const float* Lm = convL + l * 144;
            const float* Um = convU + l * 144;
            const float* Sv = convS + l * 12;
            float acc = 0.f;
            for (int a = 0; a < 12; ++a){
                float inner = 0.f;
                for (int bb2 = 0; bb2 < 12; ++bb2){
                    float m1 = (bb2 < a) ? Lm[a * 12 + bb2] : (bb2 == a ? 1.f : 0.f);
                    float m2 = (j > bb2) ? Um[bb2 * 12 + j] : (j == bb2 ? Sv[j] : 0.f);
                    inner = fmaf(m1, m2, inner);
                }
                acc = fmaf(P[i * 12 + a], inner, acc);
            }
            wsWc[idx] = acc;
        } else if (idx == 576){
            float sacc = 0.f;
            for (int q2 = 0; q2 < LLAYERS * 12; ++q2) sacc += __logf(fabsf(convS[q2]));
            wsWc[576] = sacc;
        }
    }
}

// ---------------- GEMM helpers ----------------
// first layer, conditioner: B built by shuffle from per-thread xc regs; bias folded (B slot7=1)
__device__ __forceinline__ void gemmL0c(const f16* __restrict__ ah, const f16* __restrict__ al,
                                        int xc0, int xc1, f16* actW, int lane){
    int l15 = lane & 15, g = lane >> 4;
    f16x8 Z = {};
    f16x8 Bf[4];
#pragma unroll
    for (int nt = 0; nt < 4; ++nt){
        union { uint4 u; f16x8 v; } cc;
        cc.u.x = (uint32)__shfl(xc0, nt * 16 + l15, 64);
        cc.u.y = (uint32)__shfl(xc1, nt * 16 + l15, 64);
        cc.u.z = 0u;
        cc.u.w = 0x3C000000u;   // slots 6,7 = (0, 1.0h)
        Bf[nt] = cc.v;
    }
    bool g0 = (g == 0);
#pragma unroll
    for (int mt = 0; mt < 4; ++mt){
        f16x8 Ah = g0 ? *(const f16x8*)(ah + (mt * 16 + l15) * 8) : Z;
        f16x8 Al = g0 ? *(const f16x8*)(al + (mt * 16 + l15) * 8) : Z;
#pragma unroll
        for (int nt = 0; nt < 4; ++nt){
            f32x4 acc = {0.f, 0.f, 0.f, 0.f};
            acc = MF(Ah, Bf[nt], acc);
            acc = MF(Al, Bf[nt], acc);
            uint2 v = { h2u(lk2(pkrtz(acc[0], acc[1]))), h2u(lk2(pkrtz(acc[2], acc[3]))) };
            *actWr(actW, nt * 16 + l15, mt * 32 + g * 8) = v;
        }
    }
}

// first layer, data net: B from xstS rows (bias folded, slot 7/15 = 1.0)
__device__ __forceinline__ void gemmL0n(const f16* __restrict__ ah, const f16* __restrict__ al,
                                        const f16* src, int offE,
                                        f16* actW, int lane, int widS){
    int l15 = lane & 15, g = lane >> 4;
    f16x8 Z = {};
    f16x8 Bf[4];
#pragma unroll
    for (int nt = 0; nt < 4; ++nt)
        Bf[nt] = *(const f16x8*)(src + (widS + nt * 16 + l15) * XROW + offE);
    bool g0 = (g == 0);
#pragma unroll
    for (int mt = 0; mt < 4; ++mt){
        f16x8 Ah = g0 ? *(const f16x8*)(ah + (mt * 16 + l15) * 8) : Z;
        f16x8 Al = g0 ? *(const f16x8*)(al + (mt * 16 + l15) * 8) : Z;
#pragma unroll
        for (int nt = 0; nt < 4; ++nt){
            f32x4 acc = {0.f, 0.f, 0.f, 0.f};
            acc = MF(Ah, Bf[nt], acc);
            acc = MF(Al, Bf[nt], acc);
            uint2 v = { h2u(lk2(pkrtz(acc[0], acc[1]))), h2u(lk2(pkrtz(acc[2], acc[3]))) };
            *actWr(actW, nt * 16 + l15, mt * 32 + g * 8) = v;
        }
    }
}

// hidden 64->64, in place; bias as packed half2 pairs (32 u32 per layer-half)
__device__ __forceinline__ void gemm64(const f16* __restrict__ ah, const f16* __restrict__ al,
                                       const uint32* __restrict__ bq,
                                       f16* actW, int lane){
    int l15 = lane & 15, g = lane >> 4;
    f16x8 Bf[4][2];
#pragma unroll
    for (int nt = 0; nt < 4; ++nt)
#pragma unroll
        for (int ks = 0; ks < 2; ++ks)
            Bf[nt][ks] = *actRd(actW, nt * 16 + l15, ks * 64 + g * 16);
#pragma unroll
    for (int mt = 0; mt < 4; ++mt){
        f16x8 Ah0 = *(const f16x8*)(ah + ((mt * 2 + 0) * 64 + lane) * 8);
        f16x8 Ah1 = *(const f16x8*)(ah + ((mt * 2 + 1) * 64 + lane) * 8);
        f16x8 Al0 = *(const f16x8*)(al + ((mt * 2 + 0) * 64 + lane) * 8);
        f16x8 Al1 = *(const f16x8*)(al + ((mt * 2 + 1) * 64 + lane) * 8);
        uint2 bp = *(const uint2*)(bq + mt * 8 + g * 2);
#pragma unroll
        for (int nt = 0; nt < 4; ++nt){
            f32x4 acc = {0.f, 0.f, 0.f, 0.f};
            acc = MF(Ah0, Bf[nt][0], acc);
            acc = MF(Al0, Bf[nt][0], acc);
            acc = MF(Ah1, Bf[nt][1], acc);
            acc = MF(Al1, Bf[nt][1], acc);
            uint2 v = { h2u(lk2(pkrtz(acc[0], acc[1]) + u2h(bp.x))),
                        h2u(lk2(pkrtz(acc[2], acc[3]) + u2h(bp.y))) };
            *actWr(actW, nt * 16 + l15, mt * 32 + g * 8) = v;
        }
    }
}

// spline for one chunk of 16 samples; lane L ends with 6-dim logdet sum for sample sbase+(L&15)
// deferred softplus: only the 2 selected derivative thetas get softplus'd (R8 post-mortem).
__device__ __forceinline__ float spline_chunk(const f16* thW, f16* xst,
                                              int sbase, int halfI, int lane){
    float vsum = 0.f;
#pragma unroll 1
    for (int pass = 0; pass < 2; ++pass){
        if (pass == 1 && lane >= 32) break;
        int dd = pass * 4 + (lane >> 4);
        int s16 = lane & 15;

        const f16* tr = thW + s16 * THROW + dd * 24;
        f16x8 t0 = *(const f16x8*)(tr);
        f16x8 t1 = *(const f16x8*)(tr + 8);
        f16x8 t2 = *(const f16x8*)(tr + 16);
        float th[23];
#pragma unroll
        for (int j = 0; j < 8; ++j) th[j] = (float)t0[j];
#pragma unroll
        for (int j = 0; j < 8; ++j) th[8 + j] = (float)t1[j];
#pragma unroll
        for (int j = 0; j < 7; ++j) th[16 + j] = (float)t2[j];

        float mw = th[0];
#pragma unroll
        for (int j = 1; j < KK; ++j) mw = fmaxf(mw, th[j]);
        float ew[KK]; float swsum = 0.f;
#pragma unroll
        for (int j = 0; j < KK; ++j){ ew[j] = __expf(th[j] - mw); swsum += ew[j]; }
        float iw_ = 6.0f / swsum;
        float mh = th[KK];
#pragma unroll
        for (int j = 1; j < KK; ++j) mh = fmaxf(mh, th[KK + j]);
        float eh[KK]; float shsum = 0.f;
#pragma unroll
        for (int j = 0; j < KK; ++j){ eh[j] = __expf(th[KK + j] - mh); shsum += eh[j]; }
        float ih_ = 6.0f / shsum;

        int sidx = sbase + s16;
        int slot = halfI ? dd : 8 + dd;
        float X = (float)xst[sidx * XROW + slot];
        float Xc = fminf(fmaxf(X, -BV), BV);

        // bin scan; select raw derivative thetas (sentinel -> softplus = 1.0 at ends)
        float cx = -BV, cy = -BV;
        float xk = -BV, xk1 = BV, yk = -BV, yk1 = BV;
        float tl = SENTD, trh = SENTD;
#pragma unroll
        for (int j = 0; j < KK; ++j){
            float nx = (j == KK - 1) ? (BV + 1e-6f) : (cx + ew[j] * iw_);
            float ny = (j == KK - 1) ? BV : (cy + eh[j] * ih_);
            bool sel = (j == 0) || (Xc >= cx);
            if (sel){
                xk = cx; xk1 = nx; yk = cy; yk1 = ny;
                tl = (j == 0) ? SENTD : th[15 + j];
                trh = (j == KK - 1) ? SENTD : th[16 + j];
            }
            cx = nx; cy = ny;
        }
        float dk, dk1;
        {
            float z = __expf(-fabsf(tl));
            dk = fmaxf(tl, 0.f) + __logf(1.0f + z);
            float z2 = __expf(-fabsf(trh));
            dk1 = fmaxf(trh, 0.f) + __logf(1.0f + z2);
        }
        float idx_ = 1.0f / (xk1 - xk);
        float s_ = (yk1 - yk) * idx_;
        float xi = (Xc - xk) * idx_;
        float om = 1.0f - xi;
        float xo = xi * om;
        float den = s_ + (dk1 + dk - 2.0f * s_) * xo;
        float Y = yk + (yk1 - yk) * (s_ * xi * xi + dk * xo) / den;
        float dydx = s_ * s_ * (dk1 * xi * xi + 2.0f * s_ * xo + dk * om * om) / (den * den);
        bool inside = (X <= BV) && (X >= -BV);
        float Yo = inside ? Y : X;
        float ldv = inside ? __logf(dydx) : 0.f;
        xst[sidx * XROW + slot] = (f16)Yo;
        vsum += ldv;
    }
    vsum += __shfl_xor(vsum, 16, 64);
    vsum += __shfl_xor(vsum, 32, 64);
    return vsum;
}

// paired tail: chunks NT0,NT1 share per-mt A-fragment loads. FINAL LAYER IS HI-ONLY
// (R8 post-mortem: lo-MFMAs were 24% of the MFMA stream; weight err 5e-4 ~ th f16 err).
#define TAILP(NT0, NT1, BC0A, BC0B, BC1A, BC1B)                                        \
{                                                                                      \
    f16x8 Bn0a = *actRd(actW, NT0 * 16 + l15, g * 16);                                 \
    f16x8 Bn0b = *actRd(actW, NT0 * 16 + l15, 64 + g * 16);                            \
    f16x8 Bn1a = *actRd(actW, NT1 * 16 + l15, g * 16);                                 \
    f16x8 Bn1b = *actRd(actW, NT1 * 16 + l15, 64 + g * 16);                            \
    _Pragma("unroll")                                                                  \
    for (int mt = 0; mt < 9; ++mt){                                                    \
        const f16* pch = whC + WS_WL + (mt * 128 + lane) * 8;                          \
        const f16* pnh = whN + WS_WL + (mt * 128 + lane) * 8;                          \
        f16x8 AhC0 = *(const f16x8*)(pch);                                             \
        f16x8 AhC1 = *(const f16x8*)(pch + 512);                                       \
        f16x8 AhN0 = *(const f16x8*)(pnh);                                             \
        f16x8 AhN1 = *(const f16x8*)(pnh + 512);                                       \
        uint2 cq = *(const uint2*)(bcn + mt * 8 + g * 2);                              \
        uint2 nq = *(const uint2*)(bcn + 72 + mt * 8 + g * 2);                         \
        f32x4 ac = {0.f,0.f,0.f,0.f}, an = {0.f,0.f,0.f,0.f};                          \
        ac = MF(AhC0, BC0A, ac); ac = MF(AhC1, BC0B, ac);                              \
        an = MF(AhN0, Bn0a, an); an = MF(AhN1, Bn0b, an);                              \
        h2 c01 = lk2(pkrtz(ac[0], ac[1]) + u2h(cq.x));                                 \
        h2 c23 = lk2(pkrtz(ac[2], ac[3]) + u2h(cq.y));                                 \
        h2 n01 = lk2(pkrtz(an[0], an[1]) + u2h(nq.x));                                 \
        h2 n23 = lk2(pkrtz(an[2], an[3]) + u2h(nq.y));                                 \
        uint2 tv0 = { h2u(c01 * n01), h2u(c23 * n23) };                                \
        *(uint2*)(thW + l15 * THROW + mt * 16 + g4) = tv0;                             \
        f32x4 ac2 = {0.f,0.f,0.f,0.f}, an2 = {0.f,0.f,0.f,0.f};                        \
        ac2 = MF(AhC0, BC1A, ac2); ac2 = MF(AhC1, BC1B, ac2);                          \
        an2 = MF(AhN0, Bn1a, an2); an2 = MF(AhN1, Bn1b, an2);                          \
        h2 d01 = lk2(pkrtz(ac2[0], ac2[1]) + u2h(cq.x));                               \
        h2 d23 = lk2(pkrtz(ac2[2], ac2[3]) + u2h(cq.y));                               \
        h2 m01 = lk2(pkrtz(an2[0], an2[1]) + u2h(nq.x));                               \
        h2 m23 = lk2(pkrtz(an2[2], an2[3]) + u2h(nq.y));                               \
        uint2 tv1 = { h2u(d01 * m01), h2u(d23 * m23) };                                \
        *(uint2*)(thW + (16 + l15) * THROW + mt * 16 + g4) = tv1;                      \
    }                                                                                  \
    { float v = spline_chunk(thW, xstS, widS + NT0 * 16, halfI, lane);                 \
      if (g == NT0) logdet += v; }                                                     \
    { float v = spline_chunk(thW + 16 * THROW, xstS, widS + NT1 * 16, halfI, lane);    \
      if (g == NT1) logdet += v; }                                                     \
}

// ---------------- main kernel ----------------
extern "C" __global__ void __launch_bounds__(BLK, 2)
nsflow_main(const float* __restrict__ x_in, const float* __restrict__ xc_in,
            const f16* __restrict__ wsh, const f16* __restrict__ wsl,
            const uint32* __restrict__ wsbc, const uint32* __restrict__ wsbh,
            const float* __restrict__ wsWc,
            float* __restrict__ out){
    __shared__ f16 xstS[256 * XROW];
    __shared__ f16 actS[4 * 64 * 64];
    __shared__ f16 thS[4 * 32 * THROW];

    int tid0 = threadIdx.x;
    int lane = tid0 & 63, wid = tid0 >> 6, widS = wid * 64;
    int l15 = lane & 15, g = lane >> 4, g4 = g * 4;
    int gsamp = blockIdx.x * BLK + tid0;

    float xr[DD];
    int xc0, xc1;
    {
        const float4* xv = (const float4*)(x_in + (size_t)gsamp * DD);
        float4 a0 = xv[0], a1 = xv[1], a2 = xv[2];
        xr[0]=a0.x; xr[1]=a0.y; xr[2]=a0.z; xr[3]=a0.w;
        xr[4]=a1.x; xr[5]=a1.y; xr[6]=a1.z; xr[7]=a1.w;
        xr[8]=a2.x; xr[9]=a2.y; xr[10]=a2.z; xr[11]=a2.w;
        float4 c0 = *(const float4*)(xc_in + (size_t)gsamp * 4);
        xc0 = (int)packh(c0.x, c0.y);
        xc1 = (int)packh(c0.z, c0.w);
    }

    float logdet = wsWc[576];   // conv logdet const (uniform -> s_load)
    f16* actW = actS + wid * 4096;
    f16* thW = thS + wid * (32 * THROW);

#pragma unroll 1
    for (int l = 0; l < LLAYERS; ++l){
        if (l > 0){
            uint4 r0 = *(const uint4*)(xstS + tid0 * XROW);
            uint4 r1 = *(const uint4*)(xstS + tid0 * XROW + 8);
            xr[0]=unpl(r0.x); xr[1]=unph(r0.x); xr[2]=unpl(r0.y); xr[3]=unph(r0.y);
            xr[4]=unpl(r0.z); xr[5]=unph(r0.z);
            xr[6]=unpl(r1.x); xr[7]=unph(r1.x); xr[8]=unpl(r1.y); xr[9]=unph(r1.y);
            xr[10]=unpl(r1.z); xr[11]=unph(r1.z);
        }
        // x = x @ Wconv[l], W rows read uniform from global (s_load, no LDS)
        float xn[DD];
#pragma unroll
        for (int j = 0; j < DD; ++j) xn[j] = 0.f;
#pragma unroll
        for (int i = 0; i < DD; ++i){
            const float4* wr = (const float4*)(wsWc + l * 144 + i * 12);
            float4 w0 = wr[0], w1 = wr[1], w2 = wr[2];
            float xi = xr[i];
            xn[0]=fmaf(xi,w0.x,xn[0]); xn[1]=fmaf(xi,w0.y,xn[1]); xn[2]=fmaf(xi,w0.z,xn[2]); xn[3]=fmaf(xi,w0.w,xn[3]);
            xn[4]=fmaf(xi,w1.x,xn[4]); xn[5]=fmaf(xi,w1.y,xn[5]); xn[6]=fmaf(xi,w1.z,xn[6]); xn[7]=fmaf(xi,w1.w,xn[7]);
            xn[8]=fmaf(xi,w2.x,xn[8]); xn[9]=fmaf(xi,w2.y,xn[9]); xn[10]=fmaf(xi,w2.z,xn[10]); xn[11]=fmaf(xi,w2.w,xn[11]);
        }
#pragma unroll
        for (int j = 0; j < DD; ++j) xr[j] = xn[j];
        // stage x: slots 0-5 = xr[0..5], 8-13 = xr[6..11]; slots 7,15 = 1.0 (bias-fold input)
        {
            uint4 s0 = { packh(xr[0],xr[1]), packh(xr[2],xr[3]), packh(xr[4],xr[5]), 0x3C000000u };
            uint4 s1 = { packh(xr[6],xr[7]), packh(xr[8],xr[9]), packh(xr[10],xr[11]), 0x3C000000u };
            *(uint4*)(xstS + tid0 * XROW) = s0;
            *(uint4*)(xstS + tid0 * XROW + 8) = s1;
        }

#pragma unroll 1
        for (int halfI = 0; halfI < 2; ++halfI){
            const f16* whC = wsh + (size_t)(l * 4 + halfI * 2) * NLW;
            const f16* wlC = wsl + (size_t)(l * 4 + halfI * 2) * NLW;
            const f16* whN = whC + NLW;
            const f16* wlN = wlC + NLW;
            const uint32* bhC = wsbh + (l * 4 + halfI * 2) * 64;
            const uint32* bhN = bhC + 64;
            const uint32* bcn = wsbc + (l * 2 + halfI) * 144;

            // conditioner chain
            gemmL0c(whC, wlC, xc0, xc1, actW, lane);
            gemm64(whC + WS_WH, wlC + WS_WH, bhC, actW, lane);
            gemm64(whC + WS_WH + 4096, wlC + WS_WH + 4096, bhC + 32, actW, lane);
            // snapshot conditioner final-hidden B fragments (32 VGPRs)
            f16x8 Bc0a = *actRd(actW,      l15, g * 16);
            f16x8 Bc0b = *actRd(actW,      l15, 64 + g * 16);
            f16x8 Bc1a = *actRd(actW, 16 + l15, g * 16);
            f16x8 Bc1b = *actRd(actW, 16 + l15, 64 + g * 16);
            f16x8 Bc2a = *actRd(actW, 32 + l15, g * 16);
            f16x8 Bc2b = *actRd(actW, 32 + l15, 64 + g * 16);
            f16x8 Bc3a = *actRd(actW, 48 + l15, g * 16);
            f16x8 Bc3b = *actRd(actW, 48 + l15, 64 + g * 16);

            // data chain (overwrites actW)
            gemmL0n(whN, wlN, xstS, halfI * 8, actW, lane, widS);
            gemm64(whN + WS_WH, wlN + WS_WH, bhN, actW, lane);
            gemm64(whN + WS_WH + 4096, wlN + WS_WH + 4096, bhN + 32, actW, lane);

            // fused finals + splines, paired chunks sharing A-fragment loads
            TAILP(0, 1, Bc0a, Bc0b, Bc1a, Bc1b)
            TAILP(2, 3, Bc2a, Bc2b, Bc3a, Bc3b)
        }
    }

    {
        uint4 r0 = *(const uint4*)(xstS + tid0 * XROW);
        uint4 r1 = *(const uint4*)(xstS + tid0 * XROW + 8);
        xr[0]=unpl(r0.x); xr[1]=unph(r0.x); xr[2]=unpl(r0.y); xr[3]=unph(r0.y);
        xr[4]=unpl(r0.z); xr[5]=unph(r0.z);
        xr[6]=unpl(r1.x); xr[7]=unph(r1.x); xr[8]=unpl(r1.y); xr[9]=unph(r1.y);
        xr[10]=unpl(r1.z); xr[11]=unph(r1.z);
    }
    float pr = 0.f;
#pragma unroll
    for (int j = 0; j < DD; ++j) pr = fmaf(-0.5f * xr[j], xr[j], pr);
    pr -= DD * 0.91893853320467274f;

    float4* ov = (float4*)(out + (size_t)gsamp * DD);
    ov[0] = make_float4(xr[0], xr[1], xr[2], xr[3]);
    ov[1] = make_float4(xr[4], xr[5], xr[6], xr[7]);
    ov[2] = make_float4(xr[8], xr[9], xr[10], xr[11]);
    out[(size_t)NSAMP * DD + gsamp] = logdet;
    out[(size_t)NSAMP * DD + NSAMP + gsamp] = pr;
}

extern "C" void kernel_launch(void* const* d_in, const int* in_sizes, int n_in,
                              void* d_out, int out_size, void* d_ws, size_t ws_size,
                              hipStream_t stream) {
    (void)in_sizes; (void)n_in; (void)out_size; (void)ws_size;
    const float* a[30];
    for (int i = 0; i < 30; ++i) a[i] = (const float*)d_in[i];
    f16* wsh = (f16*)d_ws;
    f16* wsl = wsh + 16 * NLW;
    uint32* wsbc = (uint32*)(wsl + 16 * NLW);   // 8*144 u32
    uint32* wsbh = wsbc + 8 * 144;              // 16*64 u32
    float* wsWc  = (float*)(wsbh + 16 * 64);    // 577 f32; total ws ≈ 1.16 MB

    dim3 pg(74, 16);
    nsflow_prep<<<pg, 256, 0, stream>>>(
        a[6], a[8], a[10], a[7], a[9], a[11],    // net1 W0,Wh,Wl,b0,bh,bl
        a[12], a[14], a[16], a[13], a[15], a[17],// net2
        a[18], a[20], a[22], a[19], a[21], a[23],// nc1
        a[24], a[26], a[28], a[25], a[27], a[29],// nc2
        a[2], a[3], a[4], a[5],                  // convP, convS, convL, convU
        wsh, wsl, wsbc, wsbh, wsWc);

    nsflow_main<<<NSAMP / BLK, BLK, 0, stream>>>(
        a[0], a[1], wsh, wsl, wsbc, wsbh, wsWc, (float*)d_out);
}

// Round 10
// 191.837 us; speedup vs baseline: 1.7590x; 1.1965x over previous
//
#include <hip/hip_runtime.h>
#include <math.h>

typedef _Float16 f16;
typedef _Float16 f16x8 __attribute__((ext_vector_type(8)));
typedef __fp16 h2 __attribute__((ext_vector_type(2)));
typedef float f32x4 __attribute__((ext_vector_type(4)));
typedef unsigned int uint32;
typedef unsigned short ushort16;

#define NSAMP 131072
#define DD 12
#define LLAYERS 4
#define KK 8
#define BV 3.0f
#define BLK 256
#define NLW 17920   // f16 elems per (net,layer): 512 (W0+b0) + 8192 (Wh) + 9216 (Wl)
#define WS_WH 512
#define WS_WL 8704
#define THROW 152   // th row: 152 f16 = 304 B
#define XROW 16     // xst row: 16 f16 = 32 B
#define SENTD 0.54132485f  // softplus(SENTD) = 1.0 — endpoint-derivative sentinel

__device__ __forceinline__ uint32 packh(float a, float b){
    union { f16 h; ushort16 u; } x, y;
    x.h = (f16)a; y.h = (f16)b;
    return (uint32)x.u | ((uint32)y.u << 16);
}
__device__ __forceinline__ float unpl(uint32 v){ union { ushort16 u; f16 h; } c; c.u = (ushort16)v; return (float)c.h; }
__device__ __forceinline__ float unph(uint32 v){ union { ushort16 u; f16 h; } c; c.u = (ushort16)(v >> 16); return (float)c.h; }

__device__ __forceinline__ h2 u2h(uint32 x){ union { uint32 u; h2 h; } c; c.u = x; return c.h; }
__device__ __forceinline__ uint32 h2u(h2 x){ union { h2 h; uint32 u; } c; c.h = x; return c.u; }
// leaky(x) = max(x, 0.2x) for slope<1 — no cmp/cndmask
__device__ __forceinline__ h2 lk2(h2 x){
    h2 k = { (__fp16)0.2f, (__fp16)0.2f };
    return __builtin_elementwise_max(x, x * k);
}
__device__ __forceinline__ h2 pkrtz(float a, float b){ return __builtin_amdgcn_cvt_pkrtz(a, b); }
__device__ __forceinline__ float frcp(float x){ return __builtin_amdgcn_rcpf(x); }

__device__ __forceinline__ f32x4 MF(f16x8 a, f16x8 b, f32x4 c){
    return __builtin_amdgcn_mfma_f32_16x16x32_f16(a, b, c, 0, 0, 0);
}

// act tile: per-wave [64 samples][64 feats] f16, row=128B, XOR-swizzled by ((s&7)<<4)
__device__ __forceinline__ const f16x8* actRd(const f16* actW, int s, int fb){
    return (const f16x8*)((const char*)actW + s * 128 + (fb ^ ((s & 7) << 4)));
}
__device__ __forceinline__ uint2* actWr(f16* actW, int s, int fb){
    return (uint2*)((char*)actW + s * 128 + (fb ^ ((s & 7) << 4)));
}

// ---------------- prep: weights -> fp16 hi/lo fragments (final layer M-permuted to
// spline order m = dd*24+p); biases packed half2; conv W and logdet const ----------------
extern "C" __global__ void nsflow_prep(
        const float* __restrict__ n1W0, const float* __restrict__ n1Wh, const float* __restrict__ n1Wl,
        const float* __restrict__ n1b0, const float* __restrict__ n1bh, const float* __restrict__ n1bl,
        const float* __restrict__ n2W0, const float* __restrict__ n2Wh, const float* __restrict__ n2Wl,
        const float* __restrict__ n2b0, const float* __restrict__ n2bh, const float* __restrict__ n2bl,
        const float* __restrict__ c1W0, const float* __restrict__ c1Wh, const float* __restrict__ c1Wl,
        const float* __restrict__ c1b0, const float* __restrict__ c1bh, const float* __restrict__ c1bl,
        const float* __restrict__ c2W0, const float* __restrict__ c2Wh, const float* __restrict__ c2Wl,
        const float* __restrict__ c2b0, const float* __restrict__ c2bh, const float* __restrict__ c2bl,
        const float* __restrict__ convP, const float* __restrict__ convS,
        const float* __restrict__ convL, const float* __restrict__ convU,
        f16* __restrict__ ws_hi, f16* __restrict__ ws_lo,
        uint32* __restrict__ wsbc, uint32* __restrict__ wsbh, float* __restrict__ wsWc){
    int NL = blockIdx.y;                      // l*4 + net; net: 0=c1 1=n1 2=c2 3=n2
    int off = blockIdx.x * 256 + threadIdx.x;
    int layer = NL >> 2, net = NL & 3;

    const float *W0, *Wh, *Wl, *b0, *bh; int nin;
    if (net == 0){ W0 = c1W0; Wh = c1Wh; Wl = c1Wl; b0 = c1b0; bh = c1bh; nin = 4; }
    else if (net == 1){ W0 = n1W0; Wh = n1Wh; Wl = n1Wl; b0 = n1b0; bh = n1bh; nin = 6; }
    else if (net == 2){ W0 = c2W0; Wh = c2Wh; Wl = c2Wl; b0 = c2b0; bh = c2bh; nin = 4; }
    else { W0 = n2W0; Wh = n2Wh; Wl = n2Wl; b0 = n2b0; bh = n2bh; nin = 6; }

    if (off < 17920){
        float w = 0.f;
        if (off < 512){                          // W0^T frags: [mt(4)][16 lanes][8 j]; j==7 -> bias
            int mt = off >> 7, r = off & 127, ln = r >> 3, j = r & 7;
            int row = mt * 16 + ln;
            if (j < nin) w = W0[(layer * nin + j) * 64 + row];
            else if (j == 7) w = b0[layer * 64 + row];
        } else if (off < 8704){                  // Wh^T frags: [h(2)][mt*2+ks (8)][64 lanes][8 j]
            int o = off - 512; int h = o >> 12; o &= 4095;
            int t = o >> 9, ln = (o >> 3) & 63, j = o & 7;
            int mt = t >> 1, ks = t & 1;
            int k = ks * 32 + (ln >> 4) * 8 + j, row = mt * 16 + (ln & 15);
            w = Wh[((layer * 2 + h) * 64 + k) * 64 + row];
        } else {                                 // Wl^T frags, M-permuted: m = dd*24+p -> f = dd*23+p
            int o = off - 8704;
            int t = o >> 9, ln = (o >> 3) & 63, j = o & 7;
            int mt = t >> 1, ks = t & 1;
            int k = ks * 32 + (ln >> 4) * 8 + j, m = mt * 16 + (ln & 15);
            int dd = m / 24, p = m - dd * 24;
            if (p < 23) w = Wl[(layer * 64 + k) * 138 + dd * 23 + p];
        }
        f16 hi = (f16)w;
        f16 lo = (f16)(w - (float)hi);
        ws_hi[NL * NLW + off] = hi;
        ws_lo[NL * NLW + off] = lo;
    } else if (off < 18064){                     // final-layer bias half2 pairs (cond [0..71], net [72..143])
        int mm = off - 17920;
        if (net == 0 || net == 2){
            int halfI = net >> 1;
            int s = layer * 2 + halfI;
            bool isn = mm >= 72;
            int m0 = 2 * (isn ? mm - 72 : mm);
            const float* bb = isn ? (halfI ? n2bl : n1bl) : (halfI ? c2bl : c1bl);
            int dd0 = m0 / 24, p0 = m0 - dd0 * 24;
            int m1 = m0 + 1;
            int dd1 = m1 / 24, p1 = m1 - dd1 * 24;
            float v0 = (p0 < 23) ? bb[layer * 138 + dd0 * 23 + p0] : 0.f;
            float v1 = (p1 < 23) ? bb[layer * 138 + dd1 * 23 + p1] : 0.f;
            wsbc[s * 144 + mm] = packh(v0, v1);
        }
    } else if (off < 18128){                     // hidden bias half2 pairs: [NL][h(2)][32]
        int q = off - 18064;
        int h = q >> 5, r = q & 31, m0 = 2 * r;
        wsbh[NL * 64 + q] = packh(bh[(layer * 2 + h) * 64 + m0], bh[(layer * 2 + h) * 64 + m0 + 1]);
    } else if (off < 18705 && NL == 0){          // conv W = P(L+I)(U+diag(S)) and logdet const
        int idx = off - 18128;
        if (idx < 576){
            int l = idx / 144, r = idx - l * 144;
            int i = r / 12, j = r - i * 12;
            const float* P = convP + l * 144;
            const float* Lm = convL + l * 144;
            const float* Um = convU + l * 144;
            const float* Sv = convS + l * 12;
            float acc = 0.f;
            for (int a = 0; a < 12; ++a){
                float inner = 0.f;
                for (int bb2 = 0; bb2 < 12; ++bb2){
                    float m1 = (bb2 < a) ? Lm[a * 12 + bb2] : (bb2 == a ? 1.f : 0.f);
                    float m2 = (j > bb2) ? Um[bb2 * 12 + j] : (j == bb2 ? Sv[j] : 0.f);
                    inner = fmaf(m1, m2, inner);
                }
                acc = fmaf(P[i * 12 + a], inner, acc);
            }
            wsWc[idx] = acc;
        } else if (idx == 576){
            float sacc = 0.f;
            for (int q2 = 0; q2 < LLAYERS * 12; ++q2) sacc += __logf(fabsf(convS[q2]));
            wsWc[576] = sacc;
        }
    }
}

// ---------------- GEMM helpers ----------------
// first layer, conditioner: B built by shuffle from per-thread xc regs; bias folded (B slot7=1)
__device__ __forceinline__ void gemmL0c(const f16* __restrict__ ah, const f16* __restrict__ al,
                                        int xc0, int xc1, f16* actW, int lane){
    int l15 = lane & 15, g = lane >> 4;
    f16x8 Z = {};
    f16x8 Bf[4];
#pragma unroll
    for (int nt = 0; nt < 4; ++nt){
        union { uint4 u; f16x8 v; } cc;
        cc.u.x = (uint32)__shfl(xc0, nt * 16 + l15, 64);
        cc.u.y = (uint32)__shfl(xc1, nt * 16 + l15, 64);
        cc.u.z = 0u;
        cc.u.w = 0x3C000000u;   // slots 6,7 = (0, 1.0h)
        Bf[nt] = cc.v;
    }
    bool g0 = (g == 0);
#pragma unroll
    for (int mt = 0; mt < 4; ++mt){
        f16x8 Ah = g0 ? *(const f16x8*)(ah + (mt * 16 + l15) * 8) : Z;
        f16x8 Al = g0 ? *(const f16x8*)(al + (mt * 16 + l15) * 8) : Z;
#pragma unroll
        for (int nt = 0; nt < 4; ++nt){
            f32x4 acc = {0.f, 0.f, 0.f, 0.f};
            acc = MF(Ah, Bf[nt], acc);
            acc = MF(Al, Bf[nt], acc);
            uint2 v = { h2u(lk2(pkrtz(acc[0], acc[1]))), h2u(lk2(pkrtz(acc[2], acc[3]))) };
            *actWr(actW, nt * 16 + l15, mt * 32 + g * 8) = v;
        }
    }
}

// first layer, data net: B from xstS rows (bias folded, slot 7/15 = 1.0)
__device__ __forceinline__ void gemmL0n(const f16* __restrict__ ah, const f16* __restrict__ al,
                                        const f16* src, int offE,
                                        f16* actW, int lane, int widS){
    int l15 = lane & 15, g = lane >> 4;
    f16x8 Z = {};
    f16x8 Bf[4];
#pragma unroll
    for (int nt = 0; nt < 4; ++nt)
        Bf[nt] = *(const f16x8*)(src + (widS + nt * 16 + l15) * XROW + offE);
    bool g0 = (g == 0);
#pragma unroll
    for (int mt = 0; mt < 4; ++mt){
        f16x8 Ah = g0 ? *(const f16x8*)(ah + (mt * 16 + l15) * 8) : Z;
        f16x8 Al = g0 ? *(const f16x8*)(al + (mt * 16 + l15) * 8) : Z;
#pragma unroll
        for (int nt = 0; nt < 4; ++nt){
            f32x4 acc = {0.f, 0.f, 0.f, 0.f};
            acc = MF(Ah, Bf[nt], acc);
            acc = MF(Al, Bf[nt], acc);
            uint2 v = { h2u(lk2(pkrtz(acc[0], acc[1]))), h2u(lk2(pkrtz(acc[2], acc[3]))) };
            *actWr(actW, nt * 16 + l15, mt * 32 + g * 8) = v;
        }
    }
}

// hidden 64->64, in place, HI-ONLY (R9 post-mortem: weight-quant err << activation f16 err)
__device__ __forceinline__ void gemm64(const f16* __restrict__ ah,
                                       const uint32* __restrict__ bq,
                                       f16* actW, int lane){
    int l15 = lane & 15, g = lane >> 4;
    f16x8 Bf[4][2];
#pragma unroll
    for (int nt = 0; nt < 4; ++nt)
#pragma unroll
        for (int ks = 0; ks < 2; ++ks)
            Bf[nt][ks] = *actRd(actW, nt * 16 + l15, ks * 64 + g * 16);
#pragma unroll
    for (int mt = 0; mt < 4; ++mt){
        f16x8 Ah0 = *(const f16x8*)(ah + ((mt * 2 + 0) * 64 + lane) * 8);
        f16x8 Ah1 = *(const f16x8*)(ah + ((mt * 2 + 1) * 64 + lane) * 8);
        uint2 bp = *(const uint2*)(bq + mt * 8 + g * 2);
#pragma unroll
        for (int nt = 0; nt < 4; ++nt){
            f32x4 acc = {0.f, 0.f, 0.f, 0.f};
            acc = MF(Ah0, Bf[nt][0], acc);
            acc = MF(Ah1, Bf[nt][1], acc);
            uint2 v = { h2u(lk2(pkrtz(acc[0], acc[1]) + u2h(bp.x))),
                        h2u(lk2(pkrtz(acc[2], acc[3]) + u2h(bp.y))) };
            *actWr(actW, nt * 16 + l15, mt * 32 + g * 8) = v;
        }
    }
}

// fused spline for a PAIR of chunks: 32 samples x 6 dims = 192 tasks = 3 FULL passes
// (R9 post-mortem: 2-pass-per-chunk wasted 25% issue on the half-masked pass).
// Returns: lane L holds the 6-dim logdet sum for sample sbase + (L&31).
__device__ __forceinline__ float spline_pair(const f16* thW, f16* xst,
                                             int sbase, int halfI, int lane){
    float vsum = 0.f;
    int s32 = lane & 31;
    int hi5 = lane >> 5;
#pragma unroll 1
    for (int pass = 0; pass < 3; ++pass){
        int dd = pass * 2 + hi5;

        const f16* tr = thW + s32 * THROW + dd * 24;
        f16x8 t0 = *(const f16x8*)(tr);
        f16x8 t1 = *(const f16x8*)(tr + 8);
        f16x8 t2 = *(const f16x8*)(tr + 16);
        float th[23];
#pragma unroll
        for (int j = 0; j < 8; ++j) th[j] = (float)t0[j];
#pragma unroll
        for (int j = 0; j < 8; ++j) th[8 + j] = (float)t1[j];
#pragma unroll
        for (int j = 0; j < 7; ++j) th[16 + j] = (float)t2[j];

        float mw = th[0];
#pragma unroll
        for (int j = 1; j < KK; ++j) mw = fmaxf(mw, th[j]);
        float ew[KK]; float swsum = 0.f;
#pragma unroll
        for (int j = 0; j < KK; ++j){ ew[j] = __expf(th[j] - mw); swsum += ew[j]; }
        float iw_ = 6.0f * frcp(swsum);
        float mh = th[KK];
#pragma unroll
        for (int j = 1; j < KK; ++j) mh = fmaxf(mh, th[KK + j]);
        float eh[KK]; float shsum = 0.f;
#pragma unroll
        for (int j = 0; j < KK; ++j){ eh[j] = __expf(th[KK + j] - mh); shsum += eh[j]; }
        float ih_ = 6.0f * frcp(shsum);

        int sidx = sbase + s32;
        int slot = halfI ? dd : 8 + dd;
        float X = (float)xst[sidx * XROW + slot];
        float Xc = fminf(fmaxf(X, -BV), BV);

        // bin scan; select raw derivative thetas (sentinel -> softplus = 1.0 at ends)
        float cx = -BV, cy = -BV;
        float xk = -BV, xk1 = BV, yk = -BV, yk1 = BV;
        float tl = SENTD, trh = SENTD;
#pragma unroll
        for (int j = 0; j < KK; ++j){
            float nx = (j == KK - 1) ? (BV + 1e-6f) : (cx + ew[j] * iw_);
            float ny = (j == KK - 1) ? BV : (cy + eh[j] * ih_);
            bool sel = (j == 0) || (Xc >= cx);
            if (sel){
                xk = cx; xk1 = nx; yk = cy; yk1 = ny;
                tl = (j == 0) ? SENTD : th[15 + j];
                trh = (j == KK - 1) ? SENTD : th[16 + j];
            }
            cx = nx; cy = ny;
        }
        float dk, dk1;
        {
            float z = __expf(-fabsf(tl));
            dk = fmaxf(tl, 0.f) + __logf(1.0f + z);
            float z2 = __expf(-fabsf(trh));
            dk1 = fmaxf(trh, 0.f) + __logf(1.0f + z2);
        }
        float idx_ = frcp(xk1 - xk);
        float s_ = (yk1 - yk) * idx_;
        float xi = (Xc - xk) * idx_;
        float om = 1.0f - xi;
        float xo = xi * om;
        float den = s_ + (dk1 + dk - 2.0f * s_) * xo;
        float invden = frcp(den);
        float Y = yk + (yk1 - yk) * (s_ * xi * xi + dk * xo) * invden;
        float dydx = s_ * s_ * (dk1 * xi * xi + 2.0f * s_ * xo + dk * om * om) * invden * invden;
        bool inside = (X <= BV) && (X >= -BV);
        float Yo = inside ? Y : X;
        float ldv = inside ? __logf(dydx) : 0.f;
        xst[sidx * XROW + slot] = (f16)Yo;
        vsum += ldv;
    }
    vsum += __shfl_xor(vsum, 32, 64);
    return vsum;
}

// paired tail: chunks NT0,NT1 share per-mt A-fragment loads; final layer hi-only;
// one fused 3-pass spline for both chunks.
#define TAILP(NT0, NT1, BC0A, BC0B, BC1A, BC1B)                                        \
{                                                                                      \
    f16x8 Bn0a = *actRd(actW, NT0 * 16 + l15, g * 16);                                 \
    f16x8 Bn0b = *actRd(actW, NT0 * 16 + l15, 64 + g * 16);                            \
    f16x8 Bn1a = *actRd(actW, NT1 * 16 + l15, g * 16);                                 \
    f16x8 Bn1b = *actRd(actW, NT1 * 16 + l15, 64 + g * 16);                            \
    _Pragma("unroll")                                                                  \
    for (int mt = 0; mt < 9; ++mt){                                                    \
        const f16* pch = whC + WS_WL + (mt * 128 + lane) * 8;                          \
        const f16* pnh = whN + WS_WL + (mt * 128 + lane) * 8;                          \
        f16x8 AhC0 = *(const f16x8*)(pch);                                             \
        f16x8 AhC1 = *(const f16x8*)(pch + 512);                                       \
        f16x8 AhN0 = *(const f16x8*)(pnh);                                             \
        f16x8 AhN1 = *(const f16x8*)(pnh + 512);                                       \
        uint2 cq = *(const uint2*)(bcn + mt * 8 + g * 2);                              \
        uint2 nq = *(const uint2*)(bcn + 72 + mt * 8 + g * 2);                         \
        f32x4 ac = {0.f,0.f,0.f,0.f}, an = {0.f,0.f,0.f,0.f};                          \
        ac = MF(AhC0, BC0A, ac); ac = MF(AhC1, BC0B, ac);                              \
        an = MF(AhN0, Bn0a, an); an = MF(AhN1, Bn0b, an);                              \
        h2 c01 = lk2(pkrtz(ac[0], ac[1]) + u2h(cq.x));                                 \
        h2 c23 = lk2(pkrtz(ac[2], ac[3]) + u2h(cq.y));                                 \
        h2 n01 = lk2(pkrtz(an[0], an[1]) + u2h(nq.x));                                 \
        h2 n23 = lk2(pkrtz(an[2], an[3]) + u2h(nq.y));                                 \
        uint2 tv0 = { h2u(c01 * n01), h2u(c23 * n23) };                                \
        *(uint2*)(thW + l15 * THROW + mt * 16 + g4) = tv0;                             \
        f32x4 ac2 = {0.f,0.f,0.f,0.f}, an2 = {0.f,0.f,0.f,0.f};                        \
        ac2 = MF(AhC0, BC1A, ac2); ac2 = MF(AhC1, BC1B, ac2);                          \
        an2 = MF(AhN0, Bn1a, an2); an2 = MF(AhN1, Bn1b, an2);                          \
        h2 d01 = lk2(pkrtz(ac2[0], ac2[1]) + u2h(cq.x));                               \
        h2 d23 = lk2(pkrtz(ac2[2], ac2[3]) + u2h(cq.y));                               \
        h2 m01 = lk2(pkrtz(an2[0], an2[1]) + u2h(nq.x));                               \
        h2 m23 = lk2(pkrtz(an2[2], an2[3]) + u2h(nq.y));                               \
        uint2 tv1 = { h2u(d01 * m01), h2u(d23 * m23) };                                \
        *(uint2*)(thW + (16 + l15) * THROW + mt * 16 + g4) = tv1;                      \
    }                                                                                  \
    { float v = spline_pair(thW, xstS, widS + NT0 * 16, halfI, lane);                  \
      if ((lane >> 5) == (NT0 >> 1)) logdet += v; }                                    \
}

// ---------------- main kernel ----------------
extern "C" __global__ void __launch_bounds__(BLK, 2)
nsflow_main(const float* __restrict__ x_in, const float* __restrict__ xc_in,
            const f16* __restrict__ wsh, const f16* __restrict__ wsl,
            const uint32* __restrict__ wsbc, const uint32* __restrict__ wsbh,
            const float* __restrict__ wsWc,
            float* __restrict__ out){
    __shared__ f16 xstS[256 * XROW];
    __shared__ f16 actS[4 * 64 * 64];
    __shared__ f16 thS[4 * 32 * THROW];

    int tid0 = threadIdx.x;
    int lane = tid0 & 63, wid = tid0 >> 6, widS = wid * 64;
    int l15 = lane & 15, g = lane >> 4, g4 = g * 4;
    int gsamp = blockIdx.x * BLK + tid0;

    float xr[DD];
    int xc0, xc1;
    {
        const float4* xv = (const float4*)(x_in + (size_t)gsamp * DD);
        float4 a0 = xv[0], a1 = xv[1], a2 = xv[2];
        xr[0]=a0.x; xr[1]=a0.y; xr[2]=a0.z; xr[3]=a0.w;
        xr[4]=a1.x; xr[5]=a1.y; xr[6]=a1.z; xr[7]=a1.w;
        xr[8]=a2.x; xr[9]=a2.y; xr[10]=a2.z; xr[11]=a2.w;
        float4 c0 = *(const float4*)(xc_in + (size_t)gsamp * 4);
        xc0 = (int)packh(c0.x, c0.y);
        xc1 = (int)packh(c0.z, c0.w);
    }

    float logdet = wsWc[576];   // conv logdet const (uniform -> s_load)
    f16* actW = actS + wid * 4096;
    f16* thW = thS + wid * (32 * THROW);

#pragma unroll 1
    for (int l = 0; l < LLAYERS; ++l){
        if (l > 0){
            uint4 r0 = *(const uint4*)(xstS + tid0 * XROW);
            uint4 r1 = *(const uint4*)(xstS + tid0 * XROW + 8);
            xr[0]=unpl(r0.x); xr[1]=unph(r0.x); xr[2]=unpl(r0.y); xr[3]=unph(r0.y);
            xr[4]=unpl(r0.z); xr[5]=unph(r0.z);
            xr[6]=unpl(r1.x); xr[7]=unph(r1.x); xr[8]=unpl(r1.y); xr[9]=unph(r1.y);
            xr[10]=unpl(r1.z); xr[11]=unph(r1.z);
        }
        // x = x @ Wconv[l], W rows read uniform from global (s_load, no LDS)
        float xn[DD];
#pragma unroll
        for (int j = 0; j < DD; ++j) xn[j] = 0.f;
#pragma unroll
        for (int i = 0; i < DD; ++i){
            const float4* wr = (const float4*)(wsWc + l * 144 + i * 12);
            float4 w0 = wr[0], w1 = wr[1], w2 = wr[2];
            float xi = xr[i];
            xn[0]=fmaf(xi,w0.x,xn[0]); xn[1]=fmaf(xi,w0.y,xn[1]); xn[2]=fmaf(xi,w0.z,xn[2]); xn[3]=fmaf(xi,w0.w,xn[3]);
            xn[4]=fmaf(xi,w1.x,xn[4]); xn[5]=fmaf(xi,w1.y,xn[5]); xn[6]=fmaf(xi,w1.z,xn[6]); xn[7]=fmaf(xi,w1.w,xn[7]);
            xn[8]=fmaf(xi,w2.x,xn[8]); xn[9]=fmaf(xi,w2.y,xn[9]); xn[10]=fmaf(xi,w2.z,xn[10]); xn[11]=fmaf(xi,w2.w,xn[11]);
        }
#pragma unroll
        for (int j = 0; j < DD; ++j) xr[j] = xn[j];
        // stage x: slots 0-5 = xr[0..5], 8-13 = xr[6..11]; slots 7,15 = 1.0 (bias-fold input)
        {
            uint4 s0 = { packh(xr[0],xr[1]), packh(xr[2],xr[3]), packh(xr[4],xr[5]), 0x3C000000u };
            uint4 s1 = { packh(xr[6],xr[7]), packh(xr[8],xr[9]), packh(xr[10],xr[11]), 0x3C000000u };
            *(uint4*)(xstS + tid0 * XROW) = s0;
            *(uint4*)(xstS + tid0 * XROW + 8) = s1;
        }

#pragma unroll 1
        for (int halfI = 0; halfI < 2; ++halfI){
            const f16* whC = wsh + (size_t)(l * 4 + halfI * 2) * NLW;
            const f16* wlC = wsl + (size_t)(l * 4 + halfI * 2) * NLW;
            const f16* whN = whC + NLW;
            const f16* wlN = wlC + NLW;
            const uint32* bhC = wsbh + (l * 4 + halfI * 2) * 64;
            const uint32* bhN = bhC + 64;
            const uint32* bcn = wsbc + (l * 2 + halfI) * 144;

            // conditioner chain (hidden layers hi-only)
            gemmL0c(whC, wlC, xc0, xc1, actW, lane);
            gemm64(whC + WS_WH, bhC, actW, lane);
            gemm64(whC + WS_WH + 4096, bhC + 32, actW, lane);
            // snapshot conditioner final-hidden B fragments (32 VGPRs)
            f16x8 Bc0a = *actRd(actW,      l15, g * 16);
            f16x8 Bc0b = *actRd(actW,      l15, 64 + g * 16);
            f16x8 Bc1a = *actRd(actW, 16 + l15, g * 16);
            f16x8 Bc1b = *actRd(actW, 16 + l15, 64 + g * 16);
            f16x8 Bc2a = *actRd(actW, 32 + l15, g * 16);
            f16x8 Bc2b = *actRd(actW, 32 + l15, 64 + g * 16);
            f16x8 Bc3a = *actRd(actW, 48 + l15, g * 16);
            f16x8 Bc3b = *actRd(actW, 48 + l15, 64 + g * 16);

            // data chain (overwrites actW)
            gemmL0n(whN, wlN, xstS, halfI * 8, actW, lane, widS);
            gemm64(whN + WS_WH, bhN, actW, lane);
            gemm64(whN + WS_WH + 4096, bhN + 32, actW, lane);

            // fused finals + paired 3-pass splines
            TAILP(0, 1, Bc0a, Bc0b, Bc1a, Bc1b)
            TAILP(2, 3, Bc2a, Bc2b, Bc3a, Bc3b)
        }
    }

    {
        uint4 r0 = *(const uint4*)(xstS + tid0 * XROW);
        uint4 r1 = *(const uint4*)(xstS + tid0 * XROW + 8);
        xr[0]=unpl(r0.x); xr[1]=unph(r0.x); xr[2]=unpl(r0.y); xr[3]=unph(r0.y);
        xr[4]=unpl(r0.z); xr[5]=unph(r0.z);
        xr[6]=unpl(r1.x); xr[7]=unph(r1.x); xr[8]=unpl(r1.y); xr[9]=unph(r1.y);
        xr[10]=unpl(r1.z); xr[11]=unph(r1.z);
    }
    float pr = 0.f;
#pragma unroll
    for (int j = 0; j < DD; ++j) pr = fmaf(-0.5f * xr[j], xr[j], pr);
    pr -= DD * 0.91893853320467274f;

    float4* ov = (float4*)(out + (size_t)gsamp * DD);
    ov[0] = make_float4(xr[0], xr[1], xr[2], xr[3]);
    ov[1] = make_float4(xr[4], xr[5], xr[6], xr[7]);
    ov[2] = make_float4(xr[8], xr[9], xr[10], xr[11]);
    out[(size_t)NSAMP * DD + gsamp] = logdet;
    out[(size_t)NSAMP * DD + NSAMP + gsamp] = pr;
}

extern "C" void kernel_launch(void* const* d_in, const int* in_sizes, int n_in,
                              void* d_out, int out_size, void* d_ws, size_t ws_size,
                              hipStream_t stream) {
    (void)in_sizes; (void)n_in; (void)out_size; (void)ws_size;
    const float* a[30];
    for (int i = 0; i < 30; ++i) a[i] = (const float*)d_in[i];
    f16* wsh = (f16*)d_ws;
    f16* wsl = wsh + 16 * NLW;
    uint32* wsbc = (uint32*)(wsl + 16 * NLW);   // 8*144 u32
    uint32* wsbh = wsbc + 8 * 144;              // 16*64 u32
    float* wsWc  = (float*)(wsbh + 16 * 64);    // 577 f32; total ws ≈ 1.16 MB

    dim3 pg(74, 16);
    nsflow_prep<<<pg, 256, 0, stream>>>(
        a[6], a[8], a[10], a[7], a[9], a[11],    // net1 W0,Wh,Wl,b0,bh,bl
        a[12], a[14], a[16], a[13], a[15], a[17],// net2
        a[18], a[20], a[22], a[19], a[21], a[23],// nc1
        a[24], a[26], a[28], a[25], a[27], a[29],// nc2
        a[2], a[3], a[4], a[5],                  // convP, convS, convL, convU
        wsh, wsl, wsbc, wsbh, wsWc);

    nsflow_main<<<NSAMP / BLK, BLK, 0, stream>>>(
        a[0], a[1], wsh, wsl, wsbc, wsbh, wsWc, (float*)d_out);
}